// Round 1
// baseline (6726.202 us; speedup 1.0000x reference)
//
#include <hip/hip_runtime.h>

#define NEGV (-1.70141173e38f)   // -finfo(f32).max / 2, matches jnp reference mask fill

constexpr int E    = 512;
constexpr int NTOK = 4096;
constexpr int NPAD = 4352;   // padded seq length (both stages)
constexpr int PAD1 = 247;    // stage-B front padding (4105 -> 4352)
constexpr int NSEQ = 4105;

// ---------------- generic tiled fp32 GEMM ----------------
// C = alpha * A @ B' (+bias)(+relu), batched via grid.z with strides.
// flags: 1 = add bias, 2 = relu, 4 = B' = bdiag*I - B  (for Newton-Schulz pinv)
__global__ __launch_bounds__(256) void k_gemm(
    const float* __restrict__ A, const float* __restrict__ B,
    const float* __restrict__ bias, float* __restrict__ C,
    int M, int N, int K, long sA, long sB, long sC,
    float alpha, float bdiag, int flags)
{
  A += (long)blockIdx.z * sA;
  B += (long)blockIdx.z * sB;
  C += (long)blockIdx.z * sC;
  __shared__ float As[16][64];
  __shared__ float Bs[16][64];
  const int tid  = threadIdx.y * 16 + threadIdx.x;
  const int row0 = blockIdx.y * 64, col0 = blockIdx.x * 64;
  float acc[4][4] = {};
  for (int k0 = 0; k0 < K; k0 += 16) {   // K is always a multiple of 16 here
#pragma unroll
    for (int e = 0; e < 4; ++e) {
      int li = tid + e * 256;
      int r = li >> 4, kk = li & 15;
      float v = 0.f;
      if (row0 + r < M) v = A[(long)(row0 + r) * K + k0 + kk];
      As[kk][r] = v;
    }
#pragma unroll
    for (int e = 0; e < 4; ++e) {
      int li = tid + e * 256;
      int kk = li >> 6, cc = li & 63;
      int gk = k0 + kk, gc = col0 + cc;
      float v = 0.f;
      if (gc < N) {
        v = B[(long)gk * N + gc];
        if (flags & 4) v = bdiag * (gk == gc ? 1.f : 0.f) - v;
      }
      Bs[kk][cc] = v;
    }
    __syncthreads();
#pragma unroll
    for (int kk = 0; kk < 16; ++kk) {
      float a[4], b[4];
#pragma unroll
      for (int i = 0; i < 4; ++i) a[i] = As[kk][threadIdx.y * 4 + i];
#pragma unroll
      for (int j = 0; j < 4; ++j) b[j] = Bs[kk][threadIdx.x * 4 + j];
#pragma unroll
      for (int i = 0; i < 4; ++i)
#pragma unroll
        for (int j = 0; j < 4; ++j) acc[i][j] += a[i] * b[j];
    }
    __syncthreads();
  }
#pragma unroll
  for (int i = 0; i < 4; ++i) {
    int r = row0 + threadIdx.y * 4 + i;
    if (r >= M) continue;
#pragma unroll
    for (int j = 0; j < 4; ++j) {
      int c = col0 + threadIdx.x * 4 + j;
      if (c >= N) continue;
      float v = alpha * acc[i][j];
      if (flags & 1) v += bias[c];
      if (flags & 2) v = fmaxf(v, 0.f);
      C[(long)r * N + c] = v;
    }
  }
}

// ---------------- small utility kernels ----------------
__global__ void k_copy(const float* __restrict__ s, float* __restrict__ d, int n) {
  int i = blockIdx.x * 256 + threadIdx.x;
  if (i < n) d[i] = s[i];
}
__global__ void k_addinto(float* __restrict__ a, const float* __restrict__ b, int n) {
  int i = blockIdx.x * 256 + threadIdx.x;
  if (i < n) a[i] += b[i];
}

// row-wise LayerNorm, E=512, 256 threads (2 elems/thread)
__global__ __launch_bounds__(256) void k_ln(const float* __restrict__ x, const float* __restrict__ g,
                                            const float* __restrict__ b, float* __restrict__ y, int rows) {
  int row = blockIdx.x;
  if (row >= rows) return;
  const float* xr = x + (long)row * E;
  __shared__ float red[256];
  int t = threadIdx.x;
  float v0 = xr[t], v1 = xr[t + 256];
  red[t] = v0 + v1; __syncthreads();
  for (int o = 128; o > 0; o >>= 1) { if (t < o) red[t] += red[t + o]; __syncthreads(); }
  float mu = red[0] * (1.f / E); __syncthreads();
  float d0 = v0 - mu, d1 = v1 - mu;
  red[t] = d0 * d0 + d1 * d1; __syncthreads();
  for (int o = 128; o > 0; o >>= 1) { if (t < o) red[t] += red[t + o]; __syncthreads(); }
  float inv = 1.f / sqrtf(red[0] * (1.f / E) + 1e-5f);
  float* yr = y + (long)row * E;
  yr[t]       = d0 * inv * g[t]       + b[t];
  yr[t + 256] = d1 * inv * g[t + 256] + b[t + 256];
}

// stage-B qkv split into per-head (h, pos, d) layout with mask & q-scale
__global__ void k_split_qkv(const float* __restrict__ qkv, float* __restrict__ q,
                            float* __restrict__ k, float* __restrict__ v) {
  int i = blockIdx.x * 256 + threadIdx.x;
  if (i >= NPAD * E) return;
  int row = i >> 9, col = i & 511;
  int h = col >> 6, d = col & 63;
  float m = (row >= PAD1) ? 1.f : 0.f;
  long o = ((long)h * NPAD + row) * 64 + d;
  const float* src = qkv + (long)row * 1536;
  q[o] = src[col] * m * 0.125f;          // * DH^-0.5
  k[o] = src[512 + col] * m;
  v[o] = src[1024 + col] * m;
}

// stage-B landmark counts
__global__ void k_lm_B(float* __restrict__ divB, float* __restrict__ mlandB) {
  int i = threadIdx.x;   // 256
  int cnt = 0;
  for (int j = 0; j < 17; ++j) cnt += (i * 17 + j >= PAD1);
  divB[i] = (float)cnt + 1e-8f;
  mlandB[i] = cnt > 0 ? 1.f : 0.f;
}

__global__ void k_qlkl_B(const float* __restrict__ q, const float* __restrict__ k,
                         const float* __restrict__ divB, float* __restrict__ ql, float* __restrict__ kl) {
  int i = blockIdx.x, h = blockIdx.y, d = threadIdx.x;   // 64 threads
  float sq = 0.f, sk = 0.f;
  for (int j = 0; j < 17; ++j) {
    int p = i * 17 + j;
    sq += q[((long)h * NPAD + p) * 64 + d];
    sk += k[((long)h * NPAD + p) * 64 + d];
  }
  float dv = divB[i];
  ql[((long)h * 256 + i) * 64 + d] = sq / dv;
  kl[((long)h * 256 + i) * 64 + d] = sk / dv;
}

// fused sim2 + row-softmax -> a2 ; batch bt = cluster*8 + head (stage B: bt = head, cluster 0)
__global__ __launch_bounds__(256) void k_a2(const float* __restrict__ ql, const float* __restrict__ kl,
                                            const float* __restrict__ mland, float* __restrict__ a2) {
  int i = blockIdx.x, bt = blockIdx.y, j = threadIdx.x;
  int cl = bt >> 3;
  __shared__ float qq[64];
  __shared__ float red[256];
  if (j < 64) qq[j] = ql[((long)bt * 256 + i) * 64 + j];
  __syncthreads();
  float s = NEGV;
  if (mland[cl * 256 + i] > 0.f && mland[cl * 256 + j] > 0.f) {
    const float* kj = kl + ((long)bt * 256 + j) * 64;
    s = 0.f;
    for (int d = 0; d < 64; ++d) s += qq[d] * kj[d];
  }
  red[j] = s; __syncthreads();
  for (int o = 128; o > 0; o >>= 1) { if (j < o) red[j] = fmaxf(red[j], red[j + o]); __syncthreads(); }
  float mx = red[0]; __syncthreads();
  float e = expf(s - mx);
  red[j] = e; __syncthreads();
  for (int o = 128; o > 0; o >>= 1) { if (j < o) red[j] += red[j + o]; __syncthreads(); }
  a2[((long)bt * 256 + i) * 256 + j] = e / red[0];
}

// pinv z0 scale: per cluster, 1/(max colsum * max rowsum) over its nheads matrices
__global__ __launch_bounds__(256) void k_pinv_scale(const float* __restrict__ a2, float* __restrict__ sc, int nheads) {
  int cl = blockIdx.x, j = threadIdx.x;
  float cmax = -1e30f, rmax = -1e30f;
  for (int h = 0; h < nheads; ++h) {
    const float* mat = a2 + (long)(cl * nheads + h) * 65536;
    float cs = 0.f, rs = 0.f;
    for (int i = 0; i < 256; ++i) { cs += mat[i * 256 + j]; rs += mat[j * 256 + i]; }
    cmax = fmaxf(cmax, cs); rmax = fmaxf(rmax, rs);
  }
  __shared__ float r1[256], r2[256];
  r1[j] = cmax; r2[j] = rmax; __syncthreads();
  for (int o = 128; o > 0; o >>= 1) {
    if (j < o) { r1[j] = fmaxf(r1[j], r1[j + o]); r2[j] = fmaxf(r2[j], r2[j + o]); }
    __syncthreads();
  }
  if (j == 0) sc[cl] = 1.f / (r1[0] * r2[0]);
}

__global__ void k_z0(const float* __restrict__ a2, const float* __restrict__ sc, float* __restrict__ z, int nb) {
  long t = (long)blockIdx.x * 256 + threadIdx.x;
  if (t >= (long)nb * 65536) return;
  int bt = (int)(t >> 16); int ij = (int)(t & 65535); int i = ij >> 8, j = ij & 255;
  z[t] = a2[((long)bt << 16) + j * 256 + i] * sc[bt >> 3];
}

// fused sim3 + softmax + (a3 @ v) -> av   (stage B)
__global__ __launch_bounds__(256) void k_av_B(const float* __restrict__ ql, const float* __restrict__ k,
                                              const float* __restrict__ v, const float* __restrict__ mland,
                                              float* __restrict__ av) {
  int i = blockIdx.x, h = blockIdx.y, t = threadIdx.x;
  __shared__ float sw[NPAD];
  __shared__ float qq[64];
  __shared__ float red[256];
  if (t < 64) qq[t] = ql[((long)h * 256 + i) * 64 + t];
  __syncthreads();
  bool landi = mland[i] > 0.f;
  float lmax = NEGV;
  for (int j = t; j < NPAD; j += 256) {
    float s = NEGV;
    if (landi && j >= PAD1) {
      const float* kj = k + ((long)h * NPAD + j) * 64;
      s = 0.f;
      for (int d = 0; d < 64; ++d) s += qq[d] * kj[d];
    }
    sw[j] = s;
    lmax = fmaxf(lmax, s);
  }
  red[t] = lmax; __syncthreads();
  for (int o = 128; o > 0; o >>= 1) { if (t < o) red[t] = fmaxf(red[t], red[t + o]); __syncthreads(); }
  float mx = red[0]; __syncthreads();
  float lsum = 0.f;
  for (int j = t; j < NPAD; j += 256) { float e = expf(sw[j] - mx); sw[j] = e; lsum += e; }
  red[t] = lsum; __syncthreads();
  for (int o = 128; o > 0; o >>= 1) { if (t < o) red[t] += red[t + o]; __syncthreads(); }
  float inv = 1.f / red[0];
  __syncthreads();
  int d = t & 63, ch = t >> 6;
  float acc = 0.f;
  for (int j = PAD1 + ch; j < NPAD; j += 4)      // invalid j have v == 0
    acc += sw[j] * v[((long)h * NPAD + j) * 64 + d];
  red[t] = acc; __syncthreads();
  if (ch == 0) av[((long)h * 256 + i) * 64 + d] = (red[d] + red[64 + d] + red[128 + d] + red[192 + d]) * inv;
}

// fused sim1 + softmax + (a1 @ W) per row (stage B); W = Z @ av
__global__ __launch_bounds__(256) void k_a1_B(const float* __restrict__ q, const float* __restrict__ kl,
                                              const float* __restrict__ mland, const float* __restrict__ W,
                                              float* __restrict__ preout) {
  int prow = PAD1 + blockIdx.x, h = blockIdx.y, t = threadIdx.x;
  __shared__ float qq[64];
  __shared__ float sw[256];
  __shared__ float red[256];
  if (t < 64) qq[t] = q[((long)h * NPAD + prow) * 64 + t];
  __syncthreads();
  float s = NEGV;
  if (mland[t] > 0.f) {
    const float* kj = kl + ((long)h * 256 + t) * 64;
    s = 0.f;
    for (int d = 0; d < 64; ++d) s += qq[d] * kj[d];
  }
  red[t] = s; __syncthreads();
  for (int o = 128; o > 0; o >>= 1) { if (t < o) red[t] = fmaxf(red[t], red[t + o]); __syncthreads(); }
  float mx = red[0]; __syncthreads();
  float e = expf(s - mx);
  sw[t] = e; red[t] = e; __syncthreads();
  for (int o = 128; o > 0; o >>= 1) { if (t < o) red[t] += red[t + o]; __syncthreads(); }
  float inv = 1.f / red[0];
  __syncthreads();
  int d = t & 63, ch = t >> 6;
  float acc = 0.f;
  const float* Wb = W + (long)h * 16384;
  for (int j = ch * 64; j < ch * 64 + 64; ++j) acc += sw[j] * Wb[j * 64 + d];
  red[t] = acc; __syncthreads();
  if (ch == 0) preout[(long)prow * E + h * 64 + d] =
      (red[d] + red[64 + d] + red[128 + d] + red[192 + d]) * inv;
}

// depthwise conv (KW=33) added to preout, stage B
__global__ void k_conv_B(const float* __restrict__ v, const float* __restrict__ w, float* __restrict__ preout) {
  int prow = PAD1 + blockIdx.x;
  int t = threadIdx.x;             // 512 = (h,d)
  int h = t >> 6, d = t & 63;
  float acc = 0.f;
  for (int tt = 0; tt < 33; ++tt) {
    int p = prow + tt - 16;
    if (p >= 0 && p < NPAD) acc += v[((long)h * NPAD + p) * 64 + d] * w[h * 33 + tt];
  }
  preout[(long)prow * E + t] += acc;
}

// cluster assignment: idx[n] = argmax_c toks[n] . pmt[c]   (first max, like jnp.argmax)
__global__ void k_idx(const float* __restrict__ x, int* __restrict__ idx) {
  int n = blockIdx.x;
  const float* tok = x + (long)(9 + n) * E;
  const float* pmt = x + E;
  __shared__ float red[64];
  int t = threadIdx.x;             // 64
  int c = t >> 3, part = t & 7;
  float s = 0.f;
  for (int d = part * 64; d < part * 64 + 64; ++d) s += tok[d] * pmt[(long)c * E + d];
  red[t] = s; __syncthreads();
  if (t < 8) {
    float dot = 0.f;
    for (int p = 0; p < 8; ++p) dot += red[t * 8 + p];
    red[t] = dot;
  }
  __syncthreads();
  if (t == 0) {
    int best = 0; float bv = red[0];
    for (int c2 = 1; c2 < 8; ++c2) if (red[c2] > bv) { bv = red[c2]; best = c2; }
    idx[n] = best;
  }
}

// ptc = || pmt @ pmt^T - I ||_F
__global__ void k_ptc(const float* __restrict__ x, float* __restrict__ ptc_out) {
  int t = threadIdx.x;             // 64: (a,b)
  int a = t >> 3, b = t & 7;
  const float* pmt = x + E;
  float s = 0.f;
  for (int d = 0; d < E; ++d) s += pmt[(long)a * E + d] * pmt[(long)b * E + d];
  s -= (a == b) ? 1.f : 0.f;
  __shared__ float red[64];
  red[t] = s * s; __syncthreads();
  for (int o = 32; o > 0; o >>= 1) { if (t < o) red[t] += red[t + o]; __syncthreads(); }
  if (t == 0) *ptc_out = sqrtf(red[0]);
}

// stage-C landmark counts per cluster (padded pos 255 = prompt, 256+n = token n)
__global__ void k_lm_C(const int* __restrict__ idx, float* __restrict__ div_c, float* __restrict__ mland_c) {
  int c = blockIdx.x, i = threadIdx.x;   // 256
  int cnt = 0;
  for (int j = 0; j < 17; ++j) {
    int p = i * 17 + j;
    if (p == 255) cnt++;
    else if (p >= 256 && idx[p - 256] == c) cnt++;
  }
  div_c[c * 256 + i] = (float)cnt + 1e-8f;
  mland_c[c * 256 + i] = cnt > 0 ? 1.f : 0.f;
}

__global__ void k_qlkl_C(const float* __restrict__ qkv, const float* __restrict__ qkv_pmt,
                         const int* __restrict__ idx, const float* __restrict__ div_c,
                         float* __restrict__ qlc, float* __restrict__ klc) {
  int i = blockIdx.x, bt = blockIdx.y;   // bt = c*8+h
  int c = bt >> 3, h = bt & 7, d = threadIdx.x;   // 64 threads
  float sq = 0.f, sk = 0.f;
  for (int j = 0; j < 17; ++j) {
    int p = i * 17 + j;
    const float* src = nullptr;
    if (p == 255) src = qkv_pmt + c * 1536;
    else if (p >= 256 && idx[p - 256] == c) src = qkv + (long)(p - 256) * 1536;
    if (src) { sq += src[h * 64 + d]; sk += src[512 + h * 64 + d]; }
  }
  float dv = div_c[c * 256 + i];
  qlc[((long)bt * 256 + i) * 64 + d] = sq * 0.125f / dv;
  klc[((long)bt * 256 + i) * 64 + d] = sk / dv;
}

// fused sim3 + softmax + (a3 @ v) for stage C, reading shared qkv with per-cluster masking
__global__ __launch_bounds__(256) void k_av_C(const float* __restrict__ qlc, const float* __restrict__ qkv,
                                              const float* __restrict__ qkv_pmt, const int* __restrict__ idx,
                                              const float* __restrict__ mland_c, float* __restrict__ av) {
  int i = blockIdx.x, bt = blockIdx.y, t = threadIdx.x;
  int c = bt >> 3, h = bt & 7;
  __shared__ float sw[NPAD];
  __shared__ unsigned char sidx[NTOK];
  __shared__ float qq[64];
  __shared__ float red[256];
  for (int m = t; m < NTOK; m += 256) sidx[m] = (unsigned char)idx[m];
  if (t < 64) qq[t] = qlc[((long)bt * 256 + i) * 64 + t];
  __syncthreads();
  bool landi = mland_c[c * 256 + i] > 0.f;
  float lmax = NEGV;
  for (int j = t; j < NPAD; j += 256) {
    bool maskj = (j == 255) || (j >= 256 && sidx[j - 256] == c);
    float s = NEGV;
    if (landi && maskj) {
      const float* kj = (j == 255) ? (qkv_pmt + c * 1536 + 512 + h * 64)
                                   : (qkv + (long)(j - 256) * 1536 + 512 + h * 64);
      s = 0.f;
      for (int d = 0; d < 64; ++d) s += qq[d] * kj[d];
    }
    sw[j] = s;
    lmax = fmaxf(lmax, s);
  }
  red[t] = lmax; __syncthreads();
  for (int o = 128; o > 0; o >>= 1) { if (t < o) red[t] = fmaxf(red[t], red[t + o]); __syncthreads(); }
  float mx = red[0]; __syncthreads();
  float lsum = 0.f;
  for (int j = t; j < NPAD; j += 256) { float e = expf(sw[j] - mx); sw[j] = e; lsum += e; }
  red[t] = lsum; __syncthreads();
  for (int o = 128; o > 0; o >>= 1) { if (t < o) red[t] += red[t + o]; __syncthreads(); }
  float inv = 1.f / red[0];
  __syncthreads();
  int d = t & 63, ch = t >> 6;
  float acc = 0.f;
  for (int j = 255 + ch; j < NPAD; j += 4) {
    bool maskj = (j == 255) || (sidx[j - 256] == c);
    if (maskj) {
      float vv = (j == 255) ? qkv_pmt[c * 1536 + 1024 + h * 64 + d]
                            : qkv[(long)(j - 256) * 1536 + 1024 + h * 64 + d];
      acc += sw[j] * vv;
    }
  }
  red[t] = acc; __syncthreads();
  if (ch == 0) av[((long)bt * 256 + i) * 64 + d] = (red[d] + red[64 + d] + red[128 + d] + red[192 + d]) * inv;
}

// fused sim1 + softmax + (a1 @ Wc) — only for each token's OWN cluster row
__global__ __launch_bounds__(256) void k_a1_C(const float* __restrict__ qkv, const float* __restrict__ klc,
                                              const float* __restrict__ mland_c, const float* __restrict__ Wc,
                                              const int* __restrict__ idx, float* __restrict__ outa) {
  int n = blockIdx.x, h = blockIdx.y, t = threadIdx.x;
  int c = idx[n];
  int bt = c * 8 + h;
  __shared__ float qq[64];
  __shared__ float sw[256];
  __shared__ float red[256];
  if (t < 64) qq[t] = qkv[(long)n * 1536 + h * 64 + t] * 0.125f;
  __syncthreads();
  float s = NEGV;
  if (mland_c[c * 256 + t] > 0.f) {
    const float* kj = klc + ((long)bt * 256 + t) * 64;
    s = 0.f;
    for (int d = 0; d < 64; ++d) s += qq[d] * kj[d];
  }
  red[t] = s; __syncthreads();
  for (int o = 128; o > 0; o >>= 1) { if (t < o) red[t] = fmaxf(red[t], red[t + o]); __syncthreads(); }
  float mx = red[0]; __syncthreads();
  float e = expf(s - mx);
  sw[t] = e; red[t] = e; __syncthreads();
  for (int o = 128; o > 0; o >>= 1) { if (t < o) red[t] += red[t + o]; __syncthreads(); }
  float inv = 1.f / red[0];
  __syncthreads();
  int d = t & 63, ch = t >> 6;
  float acc = 0.f;
  const float* Wb = Wc + (long)bt * 16384;
  for (int j = ch * 64; j < ch * 64 + 64; ++j) acc += sw[j] * Wb[j * 64 + d];
  red[t] = acc; __syncthreads();
  if (ch == 0) outa[(long)n * E + h * 64 + d] =
      (red[d] + red[64 + d] + red[128 + d] + red[192 + d]) * inv;
}

// stage-C depthwise conv added to outa (per-cluster masked v, window over neighbors)
__global__ void k_conv_C(const float* __restrict__ qkv, const float* __restrict__ qkv_pmt,
                         const int* __restrict__ idx, const float* __restrict__ w,
                         float* __restrict__ outa) {
  int n = blockIdx.x, t = threadIdx.x;   // 512
  int h = t >> 6;
  int c = idx[n];
  float acc = 0.f;
  for (int tt = 0; tt < 33; ++tt) {
    int m = n + tt - 16;
    float vv = 0.f;
    if (m == -1) vv = qkv_pmt[c * 1536 + 1024 + t];
    else if (m >= 0 && m < NTOK && idx[m] == c) vv = qkv[(long)m * 1536 + 1024 + t];
    acc += vv * w[h * 33 + tt];
  }
  outa[(long)n * E + t] += acc;
}

// partial segment sums (order-invariant vs reference argsort path)
__global__ void k_seg_part(const float* __restrict__ hun, const int* __restrict__ idx,
                           float* __restrict__ part, float* __restrict__ pcnt) {
  int c = blockIdx.x, sl = blockIdx.y, d = threadIdx.x;   // 512
  float s = 0.f; int cnt = 0;
  for (int n = sl * 256; n < sl * 256 + 256; ++n) {
    if (idx[n] == c) { s += hun[(long)n * E + d]; if (d == 0) cnt++; }
  }
  part[(long)(c * 16 + sl) * E + d] = s;
  if (d == 0) pcnt[c * 16 + sl] = (float)cnt;
}

// final: LN(cls row), merge means, tok_out, logits, softmax, write 5 outputs
__global__ void k_final(const float* __restrict__ x0, const float* __restrict__ g, const float* __restrict__ b,
                        const float* __restrict__ part, const float* __restrict__ pcnt,
                        const float* __restrict__ ptc, const float* __restrict__ W3, const float* __restrict__ b3,
                        float* __restrict__ out) {
  int t = threadIdx.x;   // 512
  __shared__ float red[512];
  float xv = x0[t];
  red[t] = xv; __syncthreads();
  for (int o = 256; o > 0; o >>= 1) { if (t < o) red[t] += red[t + o]; __syncthreads(); }
  float mu = red[0] * (1.f / 512.f); __syncthreads();
  float d0 = xv - mu;
  red[t] = d0 * d0; __syncthreads();
  for (int o = 256; o > 0; o >>= 1) { if (t < o) red[t] += red[t + o]; __syncthreads(); }
  float inv = 1.f / sqrtf(red[0] * (1.f / 512.f) + 1e-5f);
  __syncthreads();
  float acc = d0 * inv * g[t] + b[t];     // hn0
  for (int c = 0; c < 8; ++c) {
    float s = 0.f, cnt = 0.f;
    for (int sl = 0; sl < 16; ++sl) { s += part[(long)(c * 16 + sl) * E + t]; cnt += pcnt[c * 16 + sl]; }
    acc += s / fmaxf(cnt, 1.f);
  }
  float tk = acc * (1.f / 9.f);
  red[t] = tk * W3[t * 2 + 0]; __syncthreads();
  for (int o = 256; o > 0; o >>= 1) { if (t < o) red[t] += red[t + o]; __syncthreads(); }
  float l0 = red[0] + b3[0]; __syncthreads();
  red[t] = tk * W3[t * 2 + 1]; __syncthreads();
  for (int o = 256; o > 0; o >>= 1) { if (t < o) red[t] += red[t + o]; __syncthreads(); }
  float l1 = red[0] + b3[1];
  if (t == 0) {
    out[0] = l0; out[1] = l1;
    float mx = fmaxf(l0, l1);
    float e0 = expf(l0 - mx), e1 = expf(l1 - mx), s = e0 + e1;
    out[2] = e0 / s; out[3] = e1 / s;
    out[4] = *ptc;
  }
}

// ---------------- host ----------------
static void gemm(hipStream_t s, const float* A, const float* B, const float* bias, float* C,
                 int M, int N, int K, int nb, long sA, long sB, long sC,
                 float alpha, float bdiag, int flags) {
  dim3 g((N + 63) / 64, (M + 63) / 64, nb), blk(16, 16);
  k_gemm<<<g, blk, 0, s>>>(A, B, bias, C, M, N, K, sA, sB, sC, alpha, bdiag, flags);
}

// 6 Newton-Schulz iterations; aI-X folded into GEMM B-operand (flags=4)
static void pinv_iters(hipStream_t s, const float* PX, float** pz_io, float** pt_io,
                       float* PT1, float* PT2, int nb) {
  float* pz = *pz_io; float* pt = *pt_io;
  for (int it = 0; it < 6; ++it) {
    gemm(s, PX, pz, nullptr, pt,  256, 256, 256, nb, 65536, 65536, 65536, 1.f,   0.f, 0);  // XZ = X@Z
    gemm(s, pt, pt, nullptr, PT1, 256, 256, 256, nb, 65536, 65536, 65536, 1.f,   7.f, 4);  // T1 = XZ@(7I-XZ)
    gemm(s, pt, PT1, nullptr, PT2,256, 256, 256, nb, 65536, 65536, 65536, 1.f,  15.f, 4);  // T2 = XZ@(15I-T1)
    gemm(s, pz, PT2, nullptr, pt, 256, 256, 256, nb, 65536, 65536, 65536, 0.25f,13.f, 4);  // Zn = .25*Z@(13I-T2)
    float* tmp = pz; pz = pt; pt = tmp;
  }
  *pz_io = pz; *pt_io = pt;
}

extern "C" void kernel_launch(void* const* d_in, const int* in_sizes, int n_in,
                              void* d_out, int out_size, void* d_ws, size_t ws_size,
                              hipStream_t stream) {
  const float* h_in  = (const float*)d_in[0];
  const float* W1    = (const float*)d_in[1];
  const float* b1    = (const float*)d_in[2];
  const float* cls   = (const float*)d_in[3];
  const float* pmt_t = (const float*)d_in[4];
  const float* ln1_g = (const float*)d_in[5];
  const float* ln1_b = (const float*)d_in[6];
  const float* Wqkv1 = (const float*)d_in[7];
  const float* Wout1 = (const float*)d_in[8];
  const float* bout1 = (const float*)d_in[9];
  const float* conv1 = (const float*)d_in[10];
  const float* ln0_g = (const float*)d_in[11];
  const float* ln0_b = (const float*)d_in[12];
  const float* Wqkv0 = (const float*)d_in[13];
  const float* Wout0 = (const float*)d_in[14];
  const float* bout0 = (const float*)d_in[15];
  const float* conv0 = (const float*)d_in[16];
  const float* lnf_g = (const float*)d_in[17];
  const float* lnf_b = (const float*)d_in[18];
  const float* W3    = (const float*)d_in[19];
  const float* b3    = (const float*)d_in[20];

  // -------- workspace layout (fp32 elements); total ~181 MB --------
  float* ws     = (float*)d_ws;
  float* SEQ    = ws;                       // 4105*512             (becomes x after +y)
  float* LNPAD  = SEQ    + 2101760;         // 4352*512 ; reused as ln_toks
  float* QKV    = LNPAD  + 2228224;         // 4352*1536; reused as qkv_toks
  float* QH     = QKV    + 6684672;         // stage B q/k/v; reused stage C
  float* SMALL  = QH     + 6684672;         // misc small buffers
  float* PREOUT = SMALL  + 2097152;         // 4352*512 ; reused as h_un
  float* YBUF   = PREOUT + 2228224;         // 4352*512
  float* PINV   = YBUF   + 2228224;         // 5 * 64*65536

  float* qB = QH;            float* kB = QH + 2228224;  float* vB = QH + 4456448;
  float* QLC = QH;           float* KLC = QH + 1048576;
  float* AVC = QH + 2097152; float* WC  = QH + 3145728; float* OUTA = QH + 4194304;

  float* SM_DIVB   = SMALL;          float* SM_MLANDB = SMALL + 256;
  float* SM_QLB    = SMALL + 512;    float* SM_KLB    = SMALL + 131584;
  float* SM_AVB    = SMALL + 262656; float* SM_WB     = SMALL + 393728;
  float* SM_SC     = SMALL + 524800;
  float* SM_LNPMT  = SMALL + 524816; float* SM_QKVPMT = SMALL + 528912;
  float* SM_DIVC   = SMALL + 541200; float* SM_MLANDC = SMALL + 543248;
  int*   SM_IDX    = (int*)(SMALL + 545296);
  float* SM_PTC    = SMALL + 549392;
  float* SM_PART   = SMALL + 549408; float* SM_PCNT   = SMALL + 614944;

  float* PX  = PINV;
  float* PZ  = PINV + 4194304;
  float* PXZ = PINV + 2L * 4194304;
  float* PT1 = PINV + 3L * 4194304;
  float* PT2 = PINV + 4L * 4194304;

  // ======== Stage A: seq = [cls; pmt; relu(h@W1+b1)] ========
  k_copy<<<dim3(2),  dim3(256), 0, stream>>>(cls,   SEQ,       512);
  k_copy<<<dim3(16), dim3(256), 0, stream>>>(pmt_t, SEQ + 512, 4096);
  gemm(stream, h_in, W1, b1, SEQ + 9 * 512, 4096, 512, 1024, 1, 0, 0, 0, 1.f, 0.f, 1 | 2);

  // ======== Stage B: layer-1 nystrom attention ========
  hipMemsetAsync(LNPAD, 0, (size_t)PAD1 * E * sizeof(float), stream);
  k_ln<<<dim3(NSEQ), dim3(256), 0, stream>>>(SEQ, ln1_g, ln1_b, LNPAD + (long)PAD1 * E, NSEQ);
  gemm(stream, LNPAD, Wqkv1, nullptr, QKV, NPAD, 1536, 512, 1, 0, 0, 0, 1.f, 0.f, 0);
  k_split_qkv<<<dim3((NPAD * E + 255) / 256), dim3(256), 0, stream>>>(QKV, qB, kB, vB);
  k_lm_B<<<dim3(1), dim3(256), 0, stream>>>(SM_DIVB, SM_MLANDB);
  k_qlkl_B<<<dim3(256, 8), dim3(64), 0, stream>>>(qB, kB, SM_DIVB, SM_QLB, SM_KLB);
  k_a2<<<dim3(256, 8), dim3(256), 0, stream>>>(SM_QLB, SM_KLB, SM_MLANDB, PX);
  k_pinv_scale<<<dim3(1), dim3(256), 0, stream>>>(PX, SM_SC, 8);
  k_z0<<<dim3((8 * 65536 + 255) / 256), dim3(256), 0, stream>>>(PX, SM_SC, PZ, 8);
  float* pz = PZ; float* pt = PXZ;
  pinv_iters(stream, PX, &pz, &pt, PT1, PT2, 8);
  k_av_B<<<dim3(256, 8), dim3(256), 0, stream>>>(SM_QLB, kB, vB, SM_MLANDB, SM_AVB);
  gemm(stream, pz, SM_AVB, nullptr, SM_WB, 256, 64, 256, 8, 65536, 16384, 16384, 1.f, 0.f, 0);
  k_a1_B<<<dim3(NSEQ, 8), dim3(256), 0, stream>>>(qB, SM_KLB, SM_MLANDB, SM_WB, PREOUT);
  k_conv_B<<<dim3(NSEQ), dim3(512), 0, stream>>>(vB, conv1, PREOUT);
  gemm(stream, PREOUT + (long)PAD1 * E, Wout1, bout1, YBUF, NSEQ, 512, 512, 1, 0, 0, 0, 1.f, 0.f, 1);
  k_addinto<<<dim3((NSEQ * E + 255) / 256), dim3(256), 0, stream>>>(SEQ, YBUF, NSEQ * E);  // x = seq + y

  // ======== Stage C prep ========
  k_idx<<<dim3(NTOK), dim3(64), 0, stream>>>(SEQ, SM_IDX);
  k_ptc<<<dim3(1), dim3(64), 0, stream>>>(SEQ, SM_PTC);
  k_ln<<<dim3(NTOK), dim3(256), 0, stream>>>(SEQ + 9 * 512, ln0_g, ln0_b, LNPAD, NTOK);
  k_ln<<<dim3(8), dim3(256), 0, stream>>>(SEQ + 512, ln0_g, ln0_b, SM_LNPMT, 8);
  gemm(stream, LNPAD, Wqkv0, nullptr, QKV, NTOK, 1536, 512, 1, 0, 0, 0, 1.f, 0.f, 0);       // shared across clusters
  gemm(stream, SM_LNPMT, Wqkv0, nullptr, SM_QKVPMT, 8, 1536, 512, 1, 0, 0, 0, 1.f, 0.f, 0);
  k_lm_C<<<dim3(8), dim3(256), 0, stream>>>(SM_IDX, SM_DIVC, SM_MLANDC);
  k_qlkl_C<<<dim3(256, 64), dim3(64), 0, stream>>>(QKV, SM_QKVPMT, SM_IDX, SM_DIVC, QLC, KLC);
  k_a2<<<dim3(256, 64), dim3(256), 0, stream>>>(QLC, KLC, SM_MLANDC, PX);
  k_pinv_scale<<<dim3(8), dim3(256), 0, stream>>>(PX, SM_SC, 8);
  k_z0<<<dim3((64 * 65536 + 255) / 256), dim3(256), 0, stream>>>(PX, SM_SC, PZ, 64);
  pz = PZ; pt = PXZ;
  pinv_iters(stream, PX, &pz, &pt, PT1, PT2, 64);
  k_av_C<<<dim3(256, 64), dim3(256), 0, stream>>>(QLC, QKV, SM_QKVPMT, SM_IDX, SM_MLANDC, AVC);
  gemm(stream, pz, AVC, nullptr, WC, 256, 64, 256, 64, 65536, 16384, 16384, 1.f, 0.f, 0);
  k_a1_C<<<dim3(NTOK, 8), dim3(256), 0, stream>>>(QKV, KLC, SM_MLANDC, WC, SM_IDX, OUTA);
  k_conv_C<<<dim3(NTOK), dim3(512), 0, stream>>>(QKV, SM_QKVPMT, SM_IDX, conv0, OUTA);
  gemm(stream, OUTA, Wout0, bout0, PREOUT, NTOK, 512, 512, 1, 0, 0, 0, 1.f, 0.f, 1);        // only owned rows
  k_addinto<<<dim3((NTOK * E + 255) / 256), dim3(256), 0, stream>>>(PREOUT, SEQ + 9 * 512, NTOK * E); // h_un = toks + out

  // ======== Final ========
  k_seg_part<<<dim3(8, 16), dim3(512), 0, stream>>>(PREOUT, SM_IDX, SM_PART, SM_PCNT);
  k_final<<<dim3(1), dim3(512), 0, stream>>>(SEQ, lnf_g, lnf_b, SM_PART, SM_PCNT, SM_PTC, W3, b3,
                                             (float*)d_out);
}

// Round 2
// 3464.286 us; speedup vs baseline: 1.9416x; 1.9416x over previous
//
#include <hip/hip_runtime.h>

#define NEGV (-1.70141173e38f)   // -finfo(f32).max / 2, matches jnp mask fill

constexpr int E    = 512;
constexpr int NTOK = 4096;
constexpr int NPAD = 4352;
constexpr int PAD1 = 247;
constexpr int NSEQ = 4105;

typedef __attribute__((ext_vector_type(8))) short short8;
typedef __attribute__((ext_vector_type(4))) float float4v;

__device__ inline float bf2f(ushort u){ return __uint_as_float(((unsigned)u)<<16); }
__device__ inline ushort f2bf(float f){
  unsigned u = __float_as_uint(f);
  unsigned r = (u + 0x7FFFu + ((u>>16)&1u)) >> 16;   // RNE
  return (ushort)r;
}

// ================= bf16 MFMA GEMM =================
// C[M][N] = alpha * A @ B (+bias +relu +resid), batched via grid.z.
// BT=1: B supplied as [N][K] row-major (i.e. B^T), contiguous staging.
// BT=0: B supplied as [K][N]; transposed during LDS staging; optional
//       diag flag: B' = bdiag*I - B (Newton-Schulz).
// flags: 1 bias, 2 relu, 4 diag(NN only), 8 resid, 16 bf16 output.
// splitK: grid.z = nb*ksplit; slice z writes C + z*sC (fp32, flags=0).
template<int BT, bool BOUNDS>
__global__ __launch_bounds__(256) void k_mm(
    const ushort* __restrict__ A, const ushort* __restrict__ B,
    const float* __restrict__ bias, const float* __restrict__ resid,
    float* __restrict__ Cf, ushort* __restrict__ Cb,
    int M, int N, int K, int ksplit,
    long sA, long sB, long sC,
    float alpha, float bdiag, int flags)
{
  const int z = blockIdx.z;
  const int batch = z / ksplit, ks = z - batch * ksplit;
  const int kslice = K / ksplit;
  const int k0base = ks * kslice;
  A += (long)batch * sA;
  B += (long)batch * sB;
  const long coff = (long)z * sC;

  __shared__ __align__(16) ushort Al[4][128][8];
  __shared__ __align__(16) ushort Bl[4][128][8];

  const int tid  = threadIdx.x;
  const int lane = tid & 63, wid = tid >> 6;
  const int wr = wid >> 1, wc = wid & 1;
  const int l4 = lane >> 4, l15 = lane & 15;
  const int row0 = blockIdx.y * 128, col0 = blockIdx.x * 128;

  float4v acc[4][4];
#pragma unroll
  for (int i = 0; i < 4; ++i)
#pragma unroll
    for (int j = 0; j < 4; ++j) acc[i][j] = (float4v){0.f,0.f,0.f,0.f};

  for (int kt = 0; kt < kslice; kt += 32) {
    const int k0 = k0base + kt;
    __syncthreads();
    // ---- stage A tile: chunks (m, kb) ----
#pragma unroll
    for (int e = 0; e < 2; ++e) {
      int id = tid * 2 + e; int m = id >> 2, kb = id & 3;
      uint4 v = make_uint4(0u,0u,0u,0u);
      int gr = row0 + m;
      if (!BOUNDS || gr < M)
        v = *reinterpret_cast<const uint4*>(A + (long)gr * K + k0 + kb * 8);
      *reinterpret_cast<uint4*>(&Al[kb][m][0]) = v;
    }
    // ---- stage B tile ----
    if (BT) {
#pragma unroll
      for (int e = 0; e < 2; ++e) {
        int id = tid * 2 + e; int n = id >> 2, kb = id & 3;
        uint4 v = make_uint4(0u,0u,0u,0u);
        int gc = col0 + n;
        if (!BOUNDS || gc < N)
          v = *reinterpret_cast<const uint4*>(B + (long)gc * K + k0 + kb * 8);
        *reinterpret_cast<uint4*>(&Bl[kb][n][0]) = v;
      }
    } else {
      int n = tid & 127, gc = col0 + n;
      bool inb = (!BOUNDS || gc < N);
#pragma unroll
      for (int e = 0; e < 2; ++e) {
        int kb = (tid >> 7) * 2 + e;
        ushort u[8];
#pragma unroll
        for (int j = 0; j < 8; ++j) {
          int gk = k0 + kb * 8 + j;
          ushort val = inb ? B[(long)gk * N + gc] : (ushort)0;
          if (flags & 4) {
            float f = bdiag * (gk == gc ? 1.f : 0.f) - bf2f(val);
            val = f2bf(f);
          }
          u[j] = val;
        }
        uint4 w;
        w.x = (unsigned)u[0] | ((unsigned)u[1] << 16);
        w.y = (unsigned)u[2] | ((unsigned)u[3] << 16);
        w.z = (unsigned)u[4] | ((unsigned)u[5] << 16);
        w.w = (unsigned)u[6] | ((unsigned)u[7] << 16);
        *reinterpret_cast<uint4*>(&Bl[kb][n][0]) = w;
      }
    }
    __syncthreads();
    // ---- compute ----
    short8 af[4], bg[4];
#pragma unroll
    for (int mi = 0; mi < 4; ++mi)
      af[mi] = *reinterpret_cast<const short8*>(&Al[l4][wr*64 + mi*16 + l15][0]);
#pragma unroll
    for (int ni = 0; ni < 4; ++ni)
      bg[ni] = *reinterpret_cast<const short8*>(&Bl[l4][wc*64 + ni*16 + l15][0]);
#pragma unroll
    for (int mi = 0; mi < 4; ++mi)
#pragma unroll
      for (int ni = 0; ni < 4; ++ni)
        acc[mi][ni] = __builtin_amdgcn_mfma_f32_16x16x32_bf16(af[mi], bg[ni], acc[mi][ni], 0, 0, 0);
  }
  // ---- epilogue ----
#pragma unroll
  for (int mi = 0; mi < 4; ++mi)
#pragma unroll
    for (int ni = 0; ni < 4; ++ni)
#pragma unroll
      for (int r = 0; r < 4; ++r) {
        int row = row0 + wr*64 + mi*16 + l4*4 + r;
        int col = col0 + wc*64 + ni*16 + l15;
        if (BOUNDS && (row >= M || col >= N)) continue;
        float v = alpha * acc[mi][ni][r];
        if (flags & 1) v += bias[col];
        if (flags & 2) v = fmaxf(v, 0.f);
        if (flags & 8) v += resid[(long)row * N + col];
        long off = coff + (long)row * N + col;
        if (flags & 16) Cb[off] = f2bf(v); else Cf[off] = v;
      }
}

static void mm(hipStream_t st, const void* A, const void* B, const float* bias, const float* resid,
               float* Cf, ushort* Cb, int M, int N, int K, int nb, int ksplit,
               long sA, long sB, long sC, float alpha, float bdiag, int flags, bool bt, bool bounds)
{
  dim3 g((N + 127) / 128, (M + 127) / 128, nb * ksplit), b(256);
  const ushort* a = (const ushort*)A; const ushort* bb = (const ushort*)B;
  if (bt) {
    if (bounds) k_mm<1, true ><<<g, b, 0, st>>>(a, bb, bias, resid, Cf, Cb, M, N, K, ksplit, sA, sB, sC, alpha, bdiag, flags);
    else        k_mm<1, false><<<g, b, 0, st>>>(a, bb, bias, resid, Cf, Cb, M, N, K, ksplit, sA, sB, sC, alpha, bdiag, flags);
  } else {
    if (bounds) k_mm<0, true ><<<g, b, 0, st>>>(a, bb, bias, resid, Cf, Cb, M, N, K, ksplit, sA, sB, sC, alpha, bdiag, flags);
    else        k_mm<0, false><<<g, b, 0, st>>>(a, bb, bias, resid, Cf, Cb, M, N, K, ksplit, sA, sB, sC, alpha, bdiag, flags);
  }
}

// ================= utility kernels =================
__global__ void k_copy(const float* __restrict__ s, float* __restrict__ d, int n) {
  int i = blockIdx.x * 256 + threadIdx.x;
  if (i < n) d[i] = s[i];
}
__global__ void k_cvt(const float* __restrict__ s, ushort* __restrict__ d, long n) {
  long i = (long)blockIdx.x * 256 + threadIdx.x;
  if (i < n) d[i] = f2bf(s[i]);
}
// transpose+convert weight: W[K][N] fp32 -> Wt[N][K] bf16 (K,N mult of 32)
__global__ void k_tcvt(const float* __restrict__ W, ushort* __restrict__ Wt, int K, int N) {
  __shared__ float tile[32][33];
  int kb = blockIdx.y * 32, nb_ = blockIdx.x * 32;
  int tx = threadIdx.x, ty = threadIdx.y;
  for (int r = ty; r < 32; r += 8) tile[r][tx] = W[(long)(kb + r) * N + nb_ + tx];
  __syncthreads();
  for (int r = ty; r < 32; r += 8) Wt[(long)(nb_ + r) * K + kb + tx] = f2bf(tile[tx][r]);
}

// LayerNorm (E=512), bf16 output
__global__ __launch_bounds__(256) void k_ln(const float* __restrict__ x, const float* __restrict__ g,
                                            const float* __restrict__ b, ushort* __restrict__ y, int rows) {
  int row = blockIdx.x;
  if (row >= rows) return;
  const float* xr = x + (long)row * E;
  __shared__ float red[256];
  int t = threadIdx.x;
  float v0 = xr[t], v1 = xr[t + 256];
  red[t] = v0 + v1; __syncthreads();
  for (int o = 128; o > 0; o >>= 1) { if (t < o) red[t] += red[t + o]; __syncthreads(); }
  float mu = red[0] * (1.f / E); __syncthreads();
  float d0 = v0 - mu, d1 = v1 - mu;
  red[t] = d0 * d0 + d1 * d1; __syncthreads();
  for (int o = 128; o > 0; o >>= 1) { if (t < o) red[t] += red[t + o]; __syncthreads(); }
  float inv = 1.f / sqrtf(red[0] * (1.f / E) + 1e-5f);
  ushort* yr = y + (long)row * E;
  yr[t]       = f2bf(d0 * inv * g[t]       + b[t]);
  yr[t + 256] = f2bf(d1 * inv * g[t + 256] + b[t + 256]);
}

// build per-head K (bf16 [h][np][64]) from QKV fp32
__global__ void k_buildK(const float* __restrict__ qkv, ushort* __restrict__ Kb, int np, int off) {
  long i = (long)blockIdx.x * 256 + threadIdx.x;
  if (i >= (long)np * 512) return;
  int p = (int)(i >> 9), t = (int)(i & 511); int h = t >> 6, d = t & 63;
  Kb[((long)h * np + p) * 64 + d] = f2bf(qkv[(long)p * 1536 + off + t]);
}
// build per-head V^T (bf16 [h][64][np]) from QKV fp32
__global__ void k_buildVt(const float* __restrict__ qkv, ushort* __restrict__ Vt, int np) {
  int h = blockIdx.y, p0 = blockIdx.x * 64;
  __shared__ float tile[64][65];
  int tx = threadIdx.x & 63, tg = threadIdx.x >> 6;
  for (int r = tg; r < 64; r += 4) tile[r][tx] = qkv[(long)(p0 + r) * 1536 + 1024 + h * 64 + tx];
  __syncthreads();
  for (int r = tg; r < 64; r += 4) Vt[((long)h * 64 + r) * np + p0 + tx] = f2bf(tile[tx][r]);
}

// stage-B landmark counts
__global__ void k_lm_B(float* __restrict__ divB, float* __restrict__ mlandB) {
  int i = threadIdx.x;
  int cnt = 0;
  for (int j = 0; j < 17; ++j) cnt += (i * 17 + j >= PAD1);
  divB[i] = (float)cnt + 1e-8f;
  mlandB[i] = cnt > 0 ? 1.f : 0.f;
}
__global__ void k_qlkl_B(const float* __restrict__ qkv, const float* __restrict__ divB,
                         float* __restrict__ ql, float* __restrict__ kl) {
  int i = blockIdx.x, h = blockIdx.y, d = threadIdx.x;
  float sq = 0.f, sk = 0.f;
  for (int j = 0; j < 17; ++j) {
    int p = i * 17 + j;
    if (p >= PAD1) {
      sq += qkv[(long)p * 1536 + h * 64 + d];
      sk += qkv[(long)p * 1536 + 512 + h * 64 + d];
    }
  }
  float dv = divB[i];
  ql[((long)h * 256 + i) * 64 + d] = sq * 0.125f / dv;
  kl[((long)h * 256 + i) * 64 + d] = sk / dv;
}

// a2 softmax from S2 fp32 -> X bf16 (row i, batch bt; uniform 1/256 if !landi)
__global__ __launch_bounds__(256) void k_a2soft(const float* __restrict__ S2, const float* __restrict__ mland,
                                                ushort* __restrict__ X) {
  int i = blockIdx.x, bt = blockIdx.y, j = threadIdx.x;
  int cl = bt >> 3;
  const float* Sr = S2 + ((long)bt * 256 + i) * 256;
  __shared__ float red[256];
  float landi = mland[cl * 256 + i];
  float out;
  if (landi > 0.f) {
    bool valid = mland[cl * 256 + j] > 0.f;
    float sv = valid ? Sr[j] : NEGV;
    red[j] = sv; __syncthreads();
    for (int o = 128; o > 0; o >>= 1) { if (j < o) red[j] = fmaxf(red[j], red[j + o]); __syncthreads(); }
    float mx = red[0]; __syncthreads();
    float e = valid ? expf(sv - mx) : 0.f;
    red[j] = e; __syncthreads();
    for (int o = 128; o > 0; o >>= 1) { if (j < o) red[j] += red[j + o]; __syncthreads(); }
    out = e / red[0];
  } else {
    out = 1.f / 256.f;
  }
  X[((long)bt * 256 + i) * 256 + j] = f2bf(out);
}

__global__ __launch_bounds__(256) void k_pinv_scale(const ushort* __restrict__ X, float* __restrict__ sc, int nheads) {
  int cl = blockIdx.x, j = threadIdx.x;
  float cmax = -1e30f, rmax = -1e30f;
  for (int h = 0; h < nheads; ++h) {
    const ushort* mat = X + (long)(cl * nheads + h) * 65536;
    float cs = 0.f, rs = 0.f;
    for (int i = 0; i < 256; ++i) { cs += bf2f(mat[i * 256 + j]); rs += bf2f(mat[j * 256 + i]); }
    cmax = fmaxf(cmax, cs); rmax = fmaxf(rmax, rs);
  }
  __shared__ float r1[256], r2[256];
  r1[j] = cmax; r2[j] = rmax; __syncthreads();
  for (int o = 128; o > 0; o >>= 1) {
    if (j < o) { r1[j] = fmaxf(r1[j], r1[j + o]); r2[j] = fmaxf(r2[j], r2[j + o]); }
    __syncthreads();
  }
  if (j == 0) sc[cl] = 1.f / (r1[0] * r2[0]);
}

__global__ void k_z0(const ushort* __restrict__ X, const float* __restrict__ sc, ushort* __restrict__ Z, int nb) {
  long t = (long)blockIdx.x * 256 + threadIdx.x;
  if (t >= (long)nb * 65536) return;
  int bt = (int)(t >> 16); int ij = (int)(t & 65535); int i = ij >> 8, j = ij & 255;
  Z[t] = f2bf(bf2f(X[((long)bt << 16) + j * 256 + i]) * sc[bt >> 3]);
}

// scores softmax -> P bf16. MODE 0: stage B (member j>=PAD1, no prompt).
// MODE 1: stage C (member idx[j]==c, prompt column from qlc . kpmt).
template<int MODE>
__global__ __launch_bounds__(256) void k_smax(const float* __restrict__ S, ushort* __restrict__ P,
                                              const float* __restrict__ mland, const int* __restrict__ idx,
                                              int c, const float* __restrict__ qlc, const float* __restrict__ kpmt,
                                              float* __restrict__ wpmt, int ncols)
{
  int i = blockIdx.x, h = blockIdx.y, t = threadIdx.x;
  const float* Sr = S + ((long)h * 256 + i) * ncols;
  ushort* Pr = P + ((long)h * 256 + i) * ncols;
  __shared__ float sv[NPAD];
  __shared__ float red[256];
  float landi = mland[i];

  float spmt = 0.f;
  if (MODE == 1) {
    const float* qr = qlc + ((long)h * 256 + i) * 64;
    const float* kr = kpmt + h * 64;
    for (int d = 0; d < 64; ++d) spmt += qr[d] * kr[d];
  }

  if (landi > 0.f) {
    float lmax = NEGV;
    for (int j = t; j < ncols; j += 256) {
      float s = Sr[j];
      sv[j] = s;
      bool mem = (MODE == 1) ? (idx[j] == c) : (j >= PAD1);
      if (mem) lmax = fmaxf(lmax, s);
    }
    if (MODE == 1) lmax = fmaxf(lmax, spmt);
    red[t] = lmax; __syncthreads();
    for (int o = 128; o > 0; o >>= 1) { if (t < o) red[t] = fmaxf(red[t], red[t + o]); __syncthreads(); }
    float mx = red[0]; __syncthreads();
    float lsum = 0.f;
    for (int j = t; j < ncols; j += 256) {
      bool mem = (MODE == 1) ? (idx[j] == c) : (j >= PAD1);
      float e = mem ? expf(sv[j] - mx) : 0.f;
      sv[j] = e;
      lsum += e;
    }
    red[t] = lsum; __syncthreads();
    for (int o = 128; o > 0; o >>= 1) { if (t < o) red[t] += red[t + o]; __syncthreads(); }
    float denom = red[0];
    if (MODE == 1) denom += expf(spmt - mx);
    float inv = 1.f / denom;
    for (int j = t; j < ncols; j += 256) Pr[j] = f2bf(sv[j] * inv);
    if (MODE == 1 && t == 0) wpmt[h * 256 + i] = expf(spmt - mx) * inv;
  } else {
    // uniform over ALL 4352 padded positions (masked v's are zero)
    const float u = 1.f / 4352.f;
    for (int j = t; j < ncols; j += 256) {
      bool mem = (MODE == 1) ? (idx[j] == c) : (j >= PAD1);
      Pr[j] = f2bf(mem ? u : 0.f);
    }
    if (MODE == 1 && t == 0) wpmt[h * 256 + i] = u;
  }
}

// reduce split-K PV slices (+ prompt term) -> av bf16
__global__ void k_avred(const float* __restrict__ sl, const float* __restrict__ wpmt,
                        const float* __restrict__ vpmt, ushort* __restrict__ avb, int ks) {
  int i = blockIdx.x, h = blockIdx.y, d = threadIdx.x;
  float s = 0.f;
  for (int k = 0; k < ks; ++k) s += sl[(((long)h * ks + k) * 256 + i) * 64 + d];
  if (wpmt) s += wpmt[h * 256 + i] * vpmt[h * 64 + d];
  avb[((long)h * 256 + i) * 64 + d] = f2bf(s);
}

// fused sim1+softmax+(a1@W) stage B (q read from QKV)
__global__ __launch_bounds__(256) void k_a1_B(const float* __restrict__ qkv, const float* __restrict__ kl,
                                              const float* __restrict__ mland, const float* __restrict__ W,
                                              float* __restrict__ preout) {
  int prow = PAD1 + blockIdx.x, h = blockIdx.y, t = threadIdx.x;
  __shared__ float qq[64];
  __shared__ float sw[256];
  __shared__ float red[256];
  if (t < 64) qq[t] = qkv[(long)prow * 1536 + h * 64 + t] * 0.125f;
  __syncthreads();
  float s = NEGV;
  if (mland[t] > 0.f) {
    const float* kj = kl + ((long)h * 256 + t) * 64;
    s = 0.f;
    for (int d = 0; d < 64; ++d) s += qq[d] * kj[d];
  }
  red[t] = s; __syncthreads();
  for (int o = 128; o > 0; o >>= 1) { if (t < o) red[t] = fmaxf(red[t], red[t + o]); __syncthreads(); }
  float mx = red[0]; __syncthreads();
  float e = expf(s - mx);
  sw[t] = e; red[t] = e; __syncthreads();
  for (int o = 128; o > 0; o >>= 1) { if (t < o) red[t] += red[t + o]; __syncthreads(); }
  float inv = 1.f / red[0];
  __syncthreads();
  int d = t & 63, ch = t >> 6;
  float acc = 0.f;
  const float* Wb = W + (long)h * 16384;
  for (int j = ch * 64; j < ch * 64 + 64; ++j) acc += sw[j] * Wb[j * 64 + d];
  red[t] = acc; __syncthreads();
  if (ch == 0) preout[(long)prow * E + h * 64 + d] =
      (red[d] + red[64 + d] + red[128 + d] + red[192 + d]) * inv;
}

__global__ void k_conv_B(const float* __restrict__ qkv, const float* __restrict__ w, float* __restrict__ preout) {
  int prow = PAD1 + blockIdx.x, t = threadIdx.x;
  int h = t >> 6;
  float acc = 0.f;
  for (int tt = 0; tt < 33; ++tt) {
    int p = prow + tt - 16;
    if (p >= 0 && p < NPAD) acc += qkv[(long)p * 1536 + 1024 + t] * w[h * 33 + tt];
  }
  preout[(long)prow * E + t] += acc;
}

__global__ void k_idx(const float* __restrict__ x, int* __restrict__ idx) {
  int n = blockIdx.x;
  const float* tok = x + (long)(9 + n) * E;
  const float* pmt = x + E;
  __shared__ float red[64];
  int t = threadIdx.x;
  int c = t >> 3, part = t & 7;
  float s = 0.f;
  for (int d = part * 64; d < part * 64 + 64; ++d) s += tok[d] * pmt[(long)c * E + d];
  red[t] = s; __syncthreads();
  if (t < 8) {
    float dot = 0.f;
    for (int p = 0; p < 8; ++p) dot += red[t * 8 + p];
    red[t] = dot;
  }
  __syncthreads();
  if (t == 0) {
    int best = 0; float bv = red[0];
    for (int c2 = 1; c2 < 8; ++c2) if (red[c2] > bv) { bv = red[c2]; best = c2; }
    idx[n] = best;
  }
}

__global__ void k_ptc(const float* __restrict__ x, float* __restrict__ ptc_out) {
  int t = threadIdx.x;
  int a = t >> 3, b = t & 7;
  const float* pmt = x + E;
  float s = 0.f;
  for (int d = 0; d < E; ++d) s += pmt[(long)a * E + d] * pmt[(long)b * E + d];
  s -= (a == b) ? 1.f : 0.f;
  __shared__ float red[64];
  red[t] = s * s; __syncthreads();
  for (int o = 32; o > 0; o >>= 1) { if (t < o) red[t] += red[t + o]; __syncthreads(); }
  if (t == 0) *ptc_out = sqrtf(red[0]);
}

__global__ void k_lm_C(const int* __restrict__ idx, float* __restrict__ div_c, float* __restrict__ mland_c) {
  int c = blockIdx.x, i = threadIdx.x;
  int cnt = 0;
  for (int j = 0; j < 17; ++j) {
    int p = i * 17 + j;
    if (p == 255) cnt++;
    else if (p >= 256 && idx[p - 256] == c) cnt++;
  }
  div_c[c * 256 + i] = (float)cnt + 1e-8f;
  mland_c[c * 256 + i] = cnt > 0 ? 1.f : 0.f;
}

__global__ void k_qlkl_C(const float* __restrict__ qkv, const float* __restrict__ qkv_pmt,
                         const int* __restrict__ idx, const float* __restrict__ div_c,
                         float* __restrict__ qlc, float* __restrict__ klc) {
  int i = blockIdx.x, bt = blockIdx.y;
  int c = bt >> 3, h = bt & 7, d = threadIdx.x;
  float sq = 0.f, sk = 0.f;
  for (int j = 0; j < 17; ++j) {
    int p = i * 17 + j;
    const float* src = nullptr;
    if (p == 255) src = qkv_pmt + c * 1536;
    else if (p >= 256 && idx[p - 256] == c) src = qkv + (long)(p - 256) * 1536;
    if (src) { sq += src[h * 64 + d]; sk += src[512 + h * 64 + d]; }
  }
  float dv = div_c[c * 256 + i];
  qlc[((long)bt * 256 + i) * 64 + d] = sq * 0.125f / dv;
  klc[((long)bt * 256 + i) * 64 + d] = sk / dv;
}

__global__ __launch_bounds__(256) void k_a1_C(const float* __restrict__ qkv, const float* __restrict__ klc,
                                              const float* __restrict__ mland_c, const float* __restrict__ Wc,
                                              const int* __restrict__ idx, float* __restrict__ outa) {
  int n = blockIdx.x, h = blockIdx.y, t = threadIdx.x;
  int c = idx[n];
  int bt = c * 8 + h;
  __shared__ float qq[64];
  __shared__ float sw[256];
  __shared__ float red[256];
  if (t < 64) qq[t] = qkv[(long)n * 1536 + h * 64 + t] * 0.125f;
  __syncthreads();
  float s = NEGV;
  if (mland_c[c * 256 + t] > 0.f) {
    const float* kj = klc + ((long)bt * 256 + t) * 64;
    s = 0.f;
    for (int d = 0; d < 64; ++d) s += qq[d] * kj[d];
  }
  red[t] = s; __syncthreads();
  for (int o = 128; o > 0; o >>= 1) { if (t < o) red[t] = fmaxf(red[t], red[t + o]); __syncthreads(); }
  float mx = red[0]; __syncthreads();
  float e = expf(s - mx);
  sw[t] = e; red[t] = e; __syncthreads();
  for (int o = 128; o > 0; o >>= 1) { if (t < o) red[t] += red[t + o]; __syncthreads(); }
  float inv = 1.f / red[0];
  __syncthreads();
  int d = t & 63, ch = t >> 6;
  float acc = 0.f;
  const float* Wb = Wc + (long)bt * 16384;
  for (int j = ch * 64; j < ch * 64 + 64; ++j) acc += sw[j] * Wb[j * 64 + d];
  red[t] = acc; __syncthreads();
  if (ch == 0) outa[(long)n * E + h * 64 + d] =
      (red[d] + red[64 + d] + red[128 + d] + red[192 + d]) * inv;
}

__global__ void k_conv_C(const float* __restrict__ qkv, const float* __restrict__ qkv_pmt,
                         const int* __restrict__ idx, const float* __restrict__ w,
                         float* __restrict__ outa) {
  int n = blockIdx.x, t = threadIdx.x;
  int h = t >> 6;
  int c = idx[n];
  float acc = 0.f;
  for (int tt = 0; tt < 33; ++tt) {
    int m = n + tt - 16;
    float vv = 0.f;
    if (m == -1) vv = qkv_pmt[c * 1536 + 1024 + t];
    else if (m >= 0 && m < NTOK && idx[m] == c) vv = qkv[(long)m * 1536 + 1024 + t];
    acc += vv * w[h * 33 + tt];
  }
  outa[(long)n * E + t] += acc;
}

__global__ void k_seg_part(const float* __restrict__ hun, const int* __restrict__ idx,
                           float* __restrict__ part, float* __restrict__ pcnt) {
  int c = blockIdx.x, sl = blockIdx.y, d = threadIdx.x;
  float s = 0.f; int cnt = 0;
  for (int n = sl * 256; n < sl * 256 + 256; ++n) {
    if (idx[n] == c) { s += hun[(long)n * E + d]; if (d == 0) cnt++; }
  }
  part[(long)(c * 16 + sl) * E + d] = s;
  if (d == 0) pcnt[c * 16 + sl] = (float)cnt;
}

__global__ void k_final(const float* __restrict__ x0, const float* __restrict__ g, const float* __restrict__ b,
                        const float* __restrict__ part, const float* __restrict__ pcnt,
                        const float* __restrict__ ptc, const float* __restrict__ W3, const float* __restrict__ b3,
                        float* __restrict__ out) {
  int t = threadIdx.x;
  __shared__ float red[512];
  float xv = x0[t];
  red[t] = xv; __syncthreads();
  for (int o = 256; o > 0; o >>= 1) { if (t < o) red[t] += red[t + o]; __syncthreads(); }
  float mu = red[0] * (1.f / 512.f); __syncthreads();
  float d0 = xv - mu;
  red[t] = d0 * d0; __syncthreads();
  for (int o = 256; o > 0; o >>= 1) { if (t < o) red[t] += red[t + o]; __syncthreads(); }
  float inv = 1.f / sqrtf(red[0] * (1.f / 512.f) + 1e-5f);
  __syncthreads();
  float acc = d0 * inv * g[t] + b[t];
  for (int c = 0; c < 8; ++c) {
    float s = 0.f, cnt = 0.f;
    for (int sl = 0; sl < 16; ++sl) { s += part[(long)(c * 16 + sl) * E + t]; cnt += pcnt[c * 16 + sl]; }
    acc += s / fmaxf(cnt, 1.f);
  }
  float tk = acc * (1.f / 9.f);
  red[t] = tk * W3[t * 2 + 0]; __syncthreads();
  for (int o = 256; o > 0; o >>= 1) { if (t < o) red[t] += red[t + o]; __syncthreads(); }
  float l0 = red[0] + b3[0]; __syncthreads();
  red[t] = tk * W3[t * 2 + 1]; __syncthreads();
  for (int o = 256; o > 0; o >>= 1) { if (t < o) red[t] += red[t + o]; __syncthreads(); }
  float l1 = red[0] + b3[1];
  if (t == 0) {
    out[0] = l0; out[1] = l1;
    float mx = fmaxf(l0, l1);
    float e0 = expf(l0 - mx), e1 = expf(l1 - mx), s = e0 + e1;
    out[2] = e0 / s; out[3] = e1 / s;
    out[4] = *ptc;
  }
}

// ================= host =================
extern "C" void kernel_launch(void* const* d_in, const int* in_sizes, int n_in,
                              void* d_out, int out_size, void* d_ws, size_t ws_size,
                              hipStream_t stream) {
  const float* h_in  = (const float*)d_in[0];
  const float* W1    = (const float*)d_in[1];
  const float* b1    = (const float*)d_in[2];
  const float* cls   = (const float*)d_in[3];
  const float* pmt_t = (const float*)d_in[4];
  const float* ln1_g = (const float*)d_in[5];
  const float* ln1_b = (const float*)d_in[6];
  const float* Wqkv1 = (const float*)d_in[7];
  const float* Wout1 = (const float*)d_in[8];
  const float* bout1 = (const float*)d_in[9];
  const float* conv1 = (const float*)d_in[10];
  const float* ln0_g = (const float*)d_in[11];
  const float* ln0_b = (const float*)d_in[12];
  const float* Wqkv0 = (const float*)d_in[13];
  const float* Wout0 = (const float*)d_in[14];
  const float* bout0 = (const float*)d_in[15];
  const float* conv0 = (const float*)d_in[16];
  const float* lnf_g = (const float*)d_in[17];
  const float* lnf_b = (const float*)d_in[18];
  const float* W3    = (const float*)d_in[19];
  const float* b3    = (const float*)d_in[20];

  // -------- workspace layout --------
  char* base = (char*)d_ws;
  size_t off = 0;
  auto alloc = [&](size_t b) -> void* {
    off = (off + 255) & ~(size_t)255;
    void* p = base + off; off += b; return p;
  };
  float*  SEQ    = (float*) alloc((size_t)NSEQ * E * 4);
  float*  QKV    = (float*) alloc((size_t)NPAD * 1536 * 4);
  float*  QKVPMT = (float*) alloc(8 * 1536 * 4);
  ushort* W1t    = (ushort*)alloc((size_t)512 * 1024 * 2);
  ushort* Wq1t   = (ushort*)alloc((size_t)1536 * 512 * 2);
  ushort* Wq0t   = (ushort*)alloc((size_t)1536 * 512 * 2);
  ushort* Wo1t   = (ushort*)alloc((size_t)512 * 512 * 2);
  ushort* Wo0t   = (ushort*)alloc((size_t)512 * 512 * 2);
  ushort* LNb    = (ushort*)alloc((size_t)NPAD * E * 2);      // also PREb/OUTAb
  ushort* LNPMTb = (ushort*)alloc(8 * 512 * 2);
  ushort* Kb     = (ushort*)alloc((size_t)NPAD * 512 * 2);
  ushort* Vtb    = (ushort*)alloc((size_t)NPAD * 512 * 2);
  ushort* Pbuf   = (ushort*)alloc((size_t)8 * 256 * NPAD * 2);
  ushort* PXb    = (ushort*)alloc((size_t)64 * 65536 * 2);
  ushort* PZa    = (ushort*)alloc((size_t)64 * 65536 * 2);
  char*   SCR    = (char*)  alloc((size_t)8 * 256 * NPAD * 4); // 35.7MB scratch
  float*  QLB    = (float*) alloc((size_t)8 * 256 * 64 * 4);
  float*  KLB    = (float*) alloc((size_t)8 * 256 * 64 * 4);
  ushort* qlbB   = (ushort*)alloc((size_t)8 * 256 * 64 * 2);
  ushort* klbB   = (ushort*)alloc((size_t)8 * 256 * 64 * 2);
  float*  QLC    = (float*) alloc((size_t)64 * 256 * 64 * 4);
  float*  KLC    = (float*) alloc((size_t)64 * 256 * 64 * 4);
  ushort* qlcb   = (ushort*)alloc((size_t)64 * 256 * 64 * 2);
  ushort* klcb   = (ushort*)alloc((size_t)64 * 256 * 64 * 2);
  float*  avsl   = (float*) alloc((size_t)64 * 16384 * 4);
  ushort* avb    = (ushort*)alloc((size_t)64 * 16384 * 2);
  float*  Wbuf   = (float*) alloc((size_t)64 * 16384 * 4);
  float*  wpmt   = (float*) alloc(8 * 256 * 4);
  float*  PREOUT = (float*) alloc((size_t)NPAD * E * 4);
  float*  OUTA   = (float*) alloc((size_t)NTOK * E * 4);
  float*  divB   = (float*) alloc(256 * 4);
  float*  mlandB = (float*) alloc(256 * 4);
  float*  divC   = (float*) alloc(8 * 256 * 4);
  float*  mlandC = (float*) alloc(8 * 256 * 4);
  int*    idx    = (int*)   alloc(NTOK * 4);
  float*  ptc    = (float*) alloc(256);
  float*  sc     = (float*) alloc(256);
  float*  part   = (float*) alloc((size_t)8 * 16 * 512 * 4);
  float*  pcnt   = (float*) alloc(8 * 16 * 4);

  // scratch overlays
  ushort* hb   = (ushort*)SCR;                         // 4096x1024 bf16 (stage A)
  float*  Sbuf = (float*)SCR;                          // scores / S2
  ushort* Ybuf = (ushort*)SCR;                         // pinv XZ / Z'
  ushort* T1   = (ushort*)(SCR + (size_t)64 * 65536 * 2);
  ushort* T2   = (ushort*)(SCR + (size_t)2 * 64 * 65536 * 2);

  // -------- weight conversions --------
  k_tcvt<<<dim3(512/32, 1024/32), dim3(32,8), 0, stream>>>(W1, W1t, 1024, 512);
  k_tcvt<<<dim3(1536/32, 512/32), dim3(32,8), 0, stream>>>(Wqkv1, Wq1t, 512, 1536);
  k_tcvt<<<dim3(1536/32, 512/32), dim3(32,8), 0, stream>>>(Wqkv0, Wq0t, 512, 1536);
  k_tcvt<<<dim3(512/32, 512/32),  dim3(32,8), 0, stream>>>(Wout1, Wo1t, 512, 512);
  k_tcvt<<<dim3(512/32, 512/32),  dim3(32,8), 0, stream>>>(Wout0, Wo0t, 512, 512);

  // ======== Stage A ========
  k_copy<<<dim3(2),  dim3(256), 0, stream>>>(cls,   SEQ,       512);
  k_copy<<<dim3(16), dim3(256), 0, stream>>>(pmt_t, SEQ + 512, 4096);
  k_cvt<<<dim3(16384), dim3(256), 0, stream>>>(h_in, hb, (long)4096 * 1024);
  mm(stream, hb, W1t, b1, nullptr, SEQ + 9 * 512, nullptr,
     4096, 512, 1024, 1, 1, 0, 0, 0, 1.f, 0.f, 1 | 2, true, false);

  // ======== Stage B ========
  hipMemsetAsync(LNb, 0, (size_t)PAD1 * E * 2, stream);
  k_ln<<<dim3(NSEQ), dim3(256), 0, stream>>>(SEQ, ln1_g, ln1_b, LNb + (long)PAD1 * E, NSEQ);
  mm(stream, LNb, Wq1t, nullptr, nullptr, QKV, nullptr,
     NPAD, 1536, 512, 1, 1, 0, 0, 0, 1.f, 0.f, 0, true, false);
  k_buildK<<<dim3((NPAD*512)/256), dim3(256), 0, stream>>>(QKV, Kb, NPAD, 512);
  k_buildVt<<<dim3(NPAD/64, 8), dim3(256), 0, stream>>>(QKV, Vtb, NPAD);
  k_lm_B<<<dim3(1), dim3(256), 0, stream>>>(divB, mlandB);
  k_qlkl_B<<<dim3(256, 8), dim3(64), 0, stream>>>(QKV, divB, QLB, KLB);
  k_cvt<<<dim3(512), dim3(256), 0, stream>>>(QLB, qlbB, (long)8*256*64);
  k_cvt<<<dim3(512), dim3(256), 0, stream>>>(KLB, klbB, (long)8*256*64);
  // a2 = softmax(ql @ kl^T)
  mm(stream, qlbB, klbB, nullptr, nullptr, Sbuf, nullptr,
     256, 256, 64, 8, 1, 16384, 16384, 65536, 1.f, 0.f, 0, true, false);
  k_a2soft<<<dim3(256, 8), dim3(256), 0, stream>>>(Sbuf, mlandB, PXb);
  k_pinv_scale<<<dim3(1), dim3(256), 0, stream>>>(PXb, sc, 8);
  k_z0<<<dim3((8*65536)/256), dim3(256), 0, stream>>>(PXb, sc, PZa, 8);
  {
    ushort* z = PZa; ushort* y = Ybuf;
    for (int it = 0; it < 6; ++it) {
      mm(stream, PXb, z,  nullptr, nullptr, nullptr, y,  256,256,256, 8,1, 65536,65536,65536, 1.f,  0.f, 16,    false, false);
      mm(stream, y,   y,  nullptr, nullptr, nullptr, T1, 256,256,256, 8,1, 65536,65536,65536, 1.f,  7.f, 16|4,  false, false);
      mm(stream, y,   T1, nullptr, nullptr, nullptr, T2, 256,256,256, 8,1, 65536,65536,65536, 1.f, 15.f, 16|4,  false, false);
      mm(stream, z,   T2, nullptr, nullptr, nullptr, y,  256,256,256, 8,1, 65536,65536,65536, 0.25f,13.f,16|4,  false, false);
      ushort* tmp = z; z = y; y = tmp;
    }  // 6 swaps -> z == PZa
  }
  // scores + softmax + PV
  mm(stream, qlbB, Kb, nullptr, nullptr, Sbuf, nullptr,
     256, NPAD, 64, 8, 1, 16384, (long)NPAD*64, (long)256*NPAD, 1.f, 0.f, 0, true, false);
  k_smax<0><<<dim3(256, 8), dim3(256), 0, stream>>>(Sbuf, Pbuf, mlandB, nullptr, 0, nullptr, nullptr, nullptr, NPAD);
  mm(stream, Pbuf, Vtb, nullptr, nullptr, avsl, nullptr,
     256, 64, NPAD, 8, 8, (long)256*NPAD, (long)64*NPAD, 16384, 1.f, 0.f, 0, true, true);
  k_avred<<<dim3(256, 8), dim3(64), 0, stream>>>(avsl, nullptr, nullptr, avb, 8);
  mm(stream, PZa, avb, nullptr, nullptr, Wbuf, nullptr,
     256, 64, 256, 8, 1, 65536, 16384, 16384, 1.f, 0.f, 0, false, true);
  k_a1_B<<<dim3(NSEQ, 8), dim3(256), 0, stream>>>(QKV, KLB, mlandB, Wbuf, PREOUT);
  k_conv_B<<<dim3(NSEQ), dim3(512), 0, stream>>>(QKV, conv1, PREOUT);
  k_cvt<<<dim3((NSEQ*512)/256 + 1), dim3(256), 0, stream>>>(PREOUT + (long)PAD1 * E, LNb, (long)NSEQ * 512);
  mm(stream, LNb, Wo1t, bout1, SEQ, SEQ, nullptr,
     NSEQ, 512, 512, 1, 1, 0, 0, 0, 1.f, 0.f, 1 | 8, true, true);   // x = seq + y

  // ======== Stage C prep ========
  k_idx<<<dim3(NTOK), dim3(64), 0, stream>>>(SEQ, idx);
  k_ptc<<<dim3(1), dim3(64), 0, stream>>>(SEQ, ptc);
  k_ln<<<dim3(NTOK), dim3(256), 0, stream>>>(SEQ + 9 * 512, ln0_g, ln0_b, LNb, NTOK);
  k_ln<<<dim3(8), dim3(256), 0, stream>>>(SEQ + 512, ln0_g, ln0_b, LNPMTb, 8);
  mm(stream, LNb, Wq0t, nullptr, nullptr, QKV, nullptr,
     NTOK, 1536, 512, 1, 1, 0, 0, 0, 1.f, 0.f, 0, true, false);
  mm(stream, LNPMTb, Wq0t, nullptr, nullptr, QKVPMT, nullptr,
     8, 1536, 512, 1, 1, 0, 0, 0, 1.f, 0.f, 0, true, true);
  k_buildK<<<dim3((NTOK*512)/256, 1), dim3(256), 0, stream>>>(QKV, Kb, NTOK, 512);
  k_buildVt<<<dim3(NTOK/64, 8), dim3(256), 0, stream>>>(QKV, Vtb, NTOK);
  k_lm_C<<<dim3(8), dim3(256), 0, stream>>>(idx, divC, mlandC);
  k_qlkl_C<<<dim3(256, 64), dim3(64), 0, stream>>>(QKV, QKVPMT, idx, divC, QLC, KLC);
  k_cvt<<<dim3(4096), dim3(256), 0, stream>>>(QLC, qlcb, (long)64*256*64);
  k_cvt<<<dim3(4096), dim3(256), 0, stream>>>(KLC, klcb, (long)64*256*64);
  mm(stream, qlcb, klcb, nullptr, nullptr, Sbuf, nullptr,
     256, 256, 64, 64, 1, 16384, 16384, 65536, 1.f, 0.f, 0, true, false);
  k_a2soft<<<dim3(256, 64), dim3(256), 0, stream>>>(Sbuf, mlandC, PXb);
  k_pinv_scale<<<dim3(8), dim3(256), 0, stream>>>(PXb, sc, 8);
  k_z0<<<dim3((64*65536)/256), dim3(256), 0, stream>>>(PXb, sc, PZa, 64);
  {
    ushort* z = PZa; ushort* y = Ybuf;
    for (int it = 0; it < 6; ++it) {
      mm(stream, PXb, z,  nullptr, nullptr, nullptr, y,  256,256,256, 64,1, 65536,65536,65536, 1.f,  0.f, 16,    false, false);
      mm(stream, y,   y,  nullptr, nullptr, nullptr, T1, 256,256,256, 64,1, 65536,65536,65536, 1.f,  7.f, 16|4,  false, false);
      mm(stream, y,   T1, nullptr, nullptr, nullptr, T2, 256,256,256, 64,1, 65536,65536,65536, 1.f, 15.f, 16|4,  false, false);
      mm(stream, z,   T2, nullptr, nullptr, nullptr, y,  256,256,256, 64,1, 65536,65536,65536, 0.25f,13.f,16|4,  false, false);
      ushort* tmp = z; z = y; y = tmp;
    }
  }
  // per-cluster attention (scores overwrite pinv scratch; PZa survives)
  for (int c = 0; c < 8; ++c) {
    mm(stream, qlcb + (long)c*8*16384, Kb, nullptr, nullptr, Sbuf, nullptr,
       256, NTOK, 64, 8, 1, 16384, (long)NTOK*64, (long)256*NTOK, 1.f, 0.f, 0, true, false);
    k_smax<1><<<dim3(256, 8), dim3(256), 0, stream>>>(Sbuf, Pbuf, mlandC + c*256, idx, c,
        QLC + (long)c*8*16384, QKVPMT + c*1536 + 512, wpmt, NTOK);
    mm(stream, Pbuf, Vtb, nullptr, nullptr, avsl, nullptr,
       256, 64, NTOK, 8, 8, (long)256*NTOK, (long)64*NTOK, 16384, 1.f, 0.f, 0, true, true);
    k_avred<<<dim3(256, 8), dim3(64), 0, stream>>>(avsl, wpmt, QKVPMT + c*1536 + 1024, avb + (long)c*8*16384, 8);
  }
  mm(stream, PZa, avb, nullptr, nullptr, Wbuf, nullptr,
     256, 64, 256, 64, 1, 65536, 16384, 16384, 1.f, 0.f, 0, false, true);
  k_a1_C<<<dim3(NTOK, 8), dim3(256), 0, stream>>>(QKV, KLC, mlandC, Wbuf, idx, OUTA);
  k_conv_C<<<dim3(NTOK), dim3(512), 0, stream>>>(QKV, QKVPMT, idx, conv0, OUTA);
  k_cvt<<<dim3((NTOK*512)/256), dim3(256), 0, stream>>>(OUTA, LNb, (long)NTOK * 512);
  mm(stream, LNb, Wo0t, bout0, SEQ + 9 * 512, PREOUT, nullptr,
     NTOK, 512, 512, 1, 1, 0, 0, 0, 1.f, 0.f, 1 | 8, true, false);   // h_un = toks + out

  // ======== Final ========
  k_seg_part<<<dim3(8, 16), dim3(512), 0, stream>>>(PREOUT, idx, part, pcnt);
  k_final<<<dim3(1), dim3(512), 0, stream>>>(SEQ, lnf_g, lnf_b, part, pcnt, ptc, W3, b3,
                                             (float*)d_out);
}

// Round 3
// 2712.061 us; speedup vs baseline: 2.4801x; 1.2774x over previous
//
#include <hip/hip_runtime.h>

#define NEGV (-1.70141173e38f)   // -finfo(f32).max / 2, matches jnp mask fill

constexpr int E    = 512;
constexpr int NTOK = 4096;
constexpr int NPAD = 4352;
constexpr int PAD1 = 247;
constexpr int NSEQ = 4105;
constexpr int NG   = 5120;   // gathered slots (8 clusters, 128-aligned segments)

typedef __attribute__((ext_vector_type(8))) short short8;
typedef __attribute__((ext_vector_type(4))) float float4v;

__device__ inline float bf2f(ushort u){ return __uint_as_float(((unsigned)u)<<16); }
__device__ inline ushort f2bf(float f){
  unsigned u = __float_as_uint(f);
  unsigned r = (u + 0x7FFFu + ((u>>16)&1u)) >> 16;   // RNE
  return (ushort)r;
}

// ================= bf16 MFMA GEMM =================
// C = alpha * A @ B (+bias +relu +resid), batched via grid.z (nb*ksplit).
// BT=1: B given as [N][K] (row stride K). BT=0: B given as [K][N], transposed
//       during staging; flag 4: B' = bdiag*I - B (Newton-Schulz).
// colsel/rowsel: per-128-block operand select: off = (sel*8 + batch)*s{A,B}.
// zmodA/zmodB (pow2): batch stride modulo. krange: per-(batch>>kshift) K window.
// flags: 1 bias, 2 relu, 4 diag-NN, 8 resid(fp32), 16 bf16 out.
template<int BT, bool BOUNDS>
__global__ __launch_bounds__(256) void k_mm(
    const ushort* __restrict__ A, const ushort* __restrict__ B,
    const float* __restrict__ bias, const float* __restrict__ resid,
    float* __restrict__ Cf, ushort* __restrict__ Cb,
    int M, int N, int K, int ksplit, int ldC,
    long sA, long sB, long sC,
    const int* __restrict__ colsel, const int* __restrict__ rowsel,
    int zmodA, int zmodB, const int* __restrict__ krange, int kshift,
    float alpha, float bdiag, int flags)
{
  const int z = blockIdx.z;
  const int batch = z / ksplit, ks = z - batch * ksplit;
  const int kslice = K / ksplit;
  int kbeg = ks * kslice, kend = kbeg + kslice;
  if (krange) { int ki = batch >> kshift; kbeg = krange[2*ki]; kend = krange[2*ki+1]; }
  long aoff;
  if (colsel) { int s = colsel[blockIdx.x]; if (s < 0) s = 0; aoff = (long)(s*8 + batch) * sA; }
  else aoff = (long)(zmodA ? (batch & (zmodA-1)) : batch) * sA;
  long boff;
  if (rowsel) { int s = rowsel[blockIdx.y]; if (s < 0) s = 0; boff = (long)(s*8 + batch) * sB; }
  else boff = (long)(zmodB ? (batch & (zmodB-1)) : batch) * sB;
  A += aoff; B += boff;
  const long coff = (long)z * sC;

  __shared__ __align__(16) ushort Al[4][128][8];
  __shared__ __align__(16) ushort Bl[4][128][8];

  const int tid  = threadIdx.x;
  const int lane = tid & 63, wid = tid >> 6;
  const int wr = wid >> 1, wc = wid & 1;
  const int l4 = lane >> 4, l15 = lane & 15;
  const int row0 = blockIdx.y * 128, col0 = blockIdx.x * 128;

  float4v acc[4][4];
#pragma unroll
  for (int i = 0; i < 4; ++i)
#pragma unroll
    for (int j = 0; j < 4; ++j) acc[i][j] = (float4v){0.f,0.f,0.f,0.f};

  for (int k0 = kbeg; k0 < kend; k0 += 32) {
    __syncthreads();
    // ---- stage A tile ----
#pragma unroll
    for (int e = 0; e < 2; ++e) {
      int id = tid * 2 + e; int m = id >> 2, kb = id & 3;
      uint4 v = make_uint4(0u,0u,0u,0u);
      int gr = row0 + m;
      if (!BOUNDS || gr < M)
        v = *reinterpret_cast<const uint4*>(A + (long)gr * K + k0 + kb * 8);
      *reinterpret_cast<uint4*>(&Al[kb][m][0]) = v;
    }
    // ---- stage B tile ----
    if (BT) {
#pragma unroll
      for (int e = 0; e < 2; ++e) {
        int id = tid * 2 + e; int n = id >> 2, kb = id & 3;
        uint4 v = make_uint4(0u,0u,0u,0u);
        int gc = col0 + n;
        if (!BOUNDS || gc < N)
          v = *reinterpret_cast<const uint4*>(B + (long)gc * K + k0 + kb * 8);
        *reinterpret_cast<uint4*>(&Bl[kb][n][0]) = v;
      }
    } else {
      int n = tid & 127, gc = col0 + n;
      bool inb = (!BOUNDS || gc < N);
#pragma unroll
      for (int e = 0; e < 2; ++e) {
        int kb = (tid >> 7) * 2 + e;
        ushort u[8];
#pragma unroll
        for (int j = 0; j < 8; ++j) {
          int gk = k0 + kb * 8 + j;
          ushort val = inb ? B[(long)gk * N + gc] : (ushort)0;
          if (flags & 4) {
            float f = bdiag * (gk == gc ? 1.f : 0.f) - bf2f(val);
            val = f2bf(f);
          }
          u[j] = val;
        }
        uint4 w;
        w.x = (unsigned)u[0] | ((unsigned)u[1] << 16);
        w.y = (unsigned)u[2] | ((unsigned)u[3] << 16);
        w.z = (unsigned)u[4] | ((unsigned)u[5] << 16);
        w.w = (unsigned)u[6] | ((unsigned)u[7] << 16);
        *reinterpret_cast<uint4*>(&Bl[kb][n][0]) = w;
      }
    }
    __syncthreads();
    // ---- compute ----
    short8 af[4], bg[4];
#pragma unroll
    for (int mi = 0; mi < 4; ++mi)
      af[mi] = *reinterpret_cast<const short8*>(&Al[l4][wr*64 + mi*16 + l15][0]);
#pragma unroll
    for (int ni = 0; ni < 4; ++ni)
      bg[ni] = *reinterpret_cast<const short8*>(&Bl[l4][wc*64 + ni*16 + l15][0]);
#pragma unroll
    for (int mi = 0; mi < 4; ++mi)
#pragma unroll
      for (int ni = 0; ni < 4; ++ni)
        acc[mi][ni] = __builtin_amdgcn_mfma_f32_16x16x32_bf16(af[mi], bg[ni], acc[mi][ni], 0, 0, 0);
  }
  // ---- epilogue ----
#pragma unroll
  for (int mi = 0; mi < 4; ++mi)
#pragma unroll
    for (int ni = 0; ni < 4; ++ni)
#pragma unroll
      for (int r = 0; r < 4; ++r) {
        int row = row0 + wr*64 + mi*16 + l4*4 + r;
        int col = col0 + wc*64 + ni*16 + l15;
        if (BOUNDS && (row >= M || col >= N)) continue;
        float v = alpha * acc[mi][ni][r];
        if (flags & 1) v += bias[col];
        if (flags & 2) v = fmaxf(v, 0.f);
        if (flags & 8) v += resid[(long)row * ldC + col];
        long off = coff + (long)row * ldC + col;
        if (flags & 16) Cb[off] = f2bf(v); else Cf[off] = v;
      }
}

static void mm(hipStream_t st, const void* A, const void* B, const float* bias, const float* resid,
               float* Cf, ushort* Cb, int M, int N, int K, int nb, int ksplit, int ldC,
               long sA, long sB, long sC,
               const int* colsel, const int* rowsel, int zmodA, int zmodB,
               const int* krange, int kshift,
               float alpha, float bdiag, int flags, bool bt, bool bounds)
{
  dim3 g((N + 127) / 128, (M + 127) / 128, nb * ksplit), b(256);
  const ushort* a = (const ushort*)A; const ushort* bb = (const ushort*)B;
  if (bt) {
    if (bounds) k_mm<1, true ><<<g, b, 0, st>>>(a, bb, bias, resid, Cf, Cb, M, N, K, ksplit, ldC, sA, sB, sC, colsel, rowsel, zmodA, zmodB, krange, kshift, alpha, bdiag, flags);
    else        k_mm<1, false><<<g, b, 0, st>>>(a, bb, bias, resid, Cf, Cb, M, N, K, ksplit, ldC, sA, sB, sC, colsel, rowsel, zmodA, zmodB, krange, kshift, alpha, bdiag, flags);
  } else {
    if (bounds) k_mm<0, true ><<<g, b, 0, st>>>(a, bb, bias, resid, Cf, Cb, M, N, K, ksplit, ldC, sA, sB, sC, colsel, rowsel, zmodA, zmodB, krange, kshift, alpha, bdiag, flags);
    else        k_mm<0, false><<<g, b, 0, st>>>(a, bb, bias, resid, Cf, Cb, M, N, K, ksplit, ldC, sA, sB, sC, colsel, rowsel, zmodA, zmodB, krange, kshift, alpha, bdiag, flags);
  }
}

// ================= utility kernels =================
__global__ void k_copy(const float* __restrict__ s, float* __restrict__ d, int n) {
  int i = blockIdx.x * 256 + threadIdx.x;
  if (i < n) d[i] = s[i];
}
__global__ void k_cvt(const float* __restrict__ s, ushort* __restrict__ d, long n) {
  long i = (long)blockIdx.x * 256 + threadIdx.x;
  if (i < n) d[i] = f2bf(s[i]);
}
__global__ void k_tcvt(const float* __restrict__ W, ushort* __restrict__ Wt, int K, int N) {
  __shared__ float tile[32][33];
  int kb = blockIdx.y * 32, nb_ = blockIdx.x * 32;
  int tx = threadIdx.x, ty = threadIdx.y;
  for (int r = ty; r < 32; r += 8) tile[r][tx] = W[(long)(kb + r) * N + nb_ + tx];
  __syncthreads();
  for (int r = ty; r < 32; r += 8) Wt[(long)(nb_ + r) * K + kb + tx] = f2bf(tile[tx][r]);
}

__global__ __launch_bounds__(256) void k_ln(const float* __restrict__ x, const float* __restrict__ g,
                                            const float* __restrict__ b, ushort* __restrict__ y, int rows) {
  int row = blockIdx.x;
  if (row >= rows) return;
  const float* xr = x + (long)row * E;
  __shared__ float red[256];
  int t = threadIdx.x;
  float v0 = xr[t], v1 = xr[t + 256];
  red[t] = v0 + v1; __syncthreads();
  for (int o = 128; o > 0; o >>= 1) { if (t < o) red[t] += red[t + o]; __syncthreads(); }
  float mu = red[0] * (1.f / E); __syncthreads();
  float d0 = v0 - mu, d1 = v1 - mu;
  red[t] = d0 * d0 + d1 * d1; __syncthreads();
  for (int o = 128; o > 0; o >>= 1) { if (t < o) red[t] += red[t + o]; __syncthreads(); }
  float inv = 1.f / sqrtf(red[0] * (1.f / E) + 1e-5f);
  ushort* yr = y + (long)row * E;
  yr[t]       = f2bf(d0 * inv * g[t]       + b[t]);
  yr[t + 256] = f2bf(d1 * inv * g[t + 256] + b[t + 256]);
}

// per-head bf16 [h][np][64] from QKV fp32, column offset off (0=q, 512=k)
__global__ void k_buildK(const float* __restrict__ qkv, ushort* __restrict__ Kb, int np, int off) {
  long i = (long)blockIdx.x * 256 + threadIdx.x;
  if (i >= (long)np * 512) return;
  int p = (int)(i >> 9), t = (int)(i & 511); int h = t >> 6, d = t & 63;
  Kb[((long)h * np + p) * 64 + d] = f2bf(qkv[(long)p * 1536 + off + t]);
}
// per-head V^T bf16 [h][64][np] from QKV fp32
__global__ void k_buildVt(const float* __restrict__ qkv, ushort* __restrict__ Vt, int np) {
  int h = blockIdx.y, p0 = blockIdx.x * 64;
  __shared__ float tile[64][65];
  int tx = threadIdx.x & 63, tg = threadIdx.x >> 6;
  for (int r = tg; r < 64; r += 4) tile[r][tx] = qkv[(long)(p0 + r) * 1536 + 1024 + h * 64 + tx];
  __syncthreads();
  for (int d = tg; d < 64; d += 4) Vt[((long)h * 64 + d) * np + p0 + tx] = f2bf(tile[tx][d]);
}

__global__ void k_lm_B(float* __restrict__ divB, float* __restrict__ mlandB) {
  int i = threadIdx.x;
  int cnt = 0;
  for (int j = 0; j < 17; ++j) cnt += (i * 17 + j >= PAD1);
  divB[i] = (float)cnt + 1e-8f;
  mlandB[i] = cnt > 0 ? 1.f : 0.f;
}
__global__ void k_qlkl_B(const float* __restrict__ qkv, const float* __restrict__ divB,
                         ushort* __restrict__ ql, ushort* __restrict__ kl) {
  int i = blockIdx.x, h = blockIdx.y, d = threadIdx.x;
  float sq = 0.f, sk = 0.f;
  for (int j = 0; j < 17; ++j) {
    int p = i * 17 + j;
    if (p >= PAD1) {
      sq += qkv[(long)p * 1536 + h * 64 + d];
      sk += qkv[(long)p * 1536 + 512 + h * 64 + d];
    }
  }
  float dv = divB[i];
  ql[((long)h * 256 + i) * 64 + d] = f2bf(sq * 0.125f / dv);
  kl[((long)h * 256 + i) * 64 + d] = f2bf(sk / dv);
}

__global__ __launch_bounds__(256) void k_a2soft(const float* __restrict__ S2, const float* __restrict__ mland,
                                                ushort* __restrict__ X) {
  int i = blockIdx.x, bt = blockIdx.y, j = threadIdx.x;
  int cl = bt >> 3;
  const float* Sr = S2 + ((long)bt * 256 + i) * 256;
  __shared__ float red[256];
  float landi = mland[cl * 256 + i];
  float out;
  if (landi > 0.f) {
    bool valid = mland[cl * 256 + j] > 0.f;
    float sv = valid ? Sr[j] : NEGV;
    red[j] = sv; __syncthreads();
    for (int o = 128; o > 0; o >>= 1) { if (j < o) red[j] = fmaxf(red[j], red[j + o]); __syncthreads(); }
    float mx = red[0]; __syncthreads();
    float e = valid ? expf(sv - mx) : 0.f;
    red[j] = e; __syncthreads();
    for (int o = 128; o > 0; o >>= 1) { if (j < o) red[j] += red[j + o]; __syncthreads(); }
    out = e / red[0];
  } else {
    out = 1.f / 256.f;
  }
  X[((long)bt * 256 + i) * 256 + j] = f2bf(out);
}

__global__ __launch_bounds__(256) void k_pinv_scale(const ushort* __restrict__ X, float* __restrict__ sc, int nheads) {
  int cl = blockIdx.x, j = threadIdx.x;
  float cmax = -1e30f, rmax = -1e30f;
  for (int h = 0; h < nheads; ++h) {
    const ushort* mat = X + (long)(cl * nheads + h) * 65536;
    float cs = 0.f, rs = 0.f;
    for (int i = 0; i < 256; ++i) { cs += bf2f(mat[i * 256 + j]); rs += bf2f(mat[j * 256 + i]); }
    cmax = fmaxf(cmax, cs); rmax = fmaxf(rmax, rs);
  }
  __shared__ float r1[256], r2[256];
  r1[j] = cmax; r2[j] = rmax; __syncthreads();
  for (int o = 128; o > 0; o >>= 1) {
    if (j < o) { r1[j] = fmaxf(r1[j], r1[j + o]); r2[j] = fmaxf(r2[j], r2[j + o]); }
    __syncthreads();
  }
  if (j == 0) sc[cl] = 1.f / (r1[0] * r2[0]);
}

__global__ void k_z0(const ushort* __restrict__ X, const float* __restrict__ sc, ushort* __restrict__ Z, int nb) {
  long t = (long)blockIdx.x * 256 + threadIdx.x;
  if (t >= (long)nb * 65536) return;
  int bt = (int)(t >> 16); int ij = (int)(t & 65535); int i = ij >> 8, j = ij & 255;
  Z[t] = f2bf(bf2f(X[((long)bt << 16) + j * 256 + i]) * sc[bt >> 3]);
}

// stage-B a3 softmax (NPAD cols, member = j>=PAD1)
__global__ __launch_bounds__(256) void k_smaxB_av(const float* __restrict__ S, ushort* __restrict__ P,
                                                  const float* __restrict__ mland) {
  int i = blockIdx.x, h = blockIdx.y, t = threadIdx.x;
  const float* Sr = S + ((long)h * 256 + i) * NPAD;
  ushort* Pr = P + ((long)h * 256 + i) * NPAD;
  __shared__ float sv[NPAD];
  __shared__ float red[256];
  if (mland[i] > 0.f) {
    float lmax = NEGV;
    for (int j = t; j < NPAD; j += 256) {
      float s = Sr[j];
      sv[j] = s;
      if (j >= PAD1) lmax = fmaxf(lmax, s);
    }
    red[t] = lmax; __syncthreads();
    for (int o = 128; o > 0; o >>= 1) { if (t < o) red[t] = fmaxf(red[t], red[t + o]); __syncthreads(); }
    float mx = red[0]; __syncthreads();
    float lsum = 0.f;
    for (int j = t; j < NPAD; j += 256) {
      float e = (j >= PAD1) ? expf(sv[j] - mx) : 0.f;
      sv[j] = e; lsum += e;
    }
    red[t] = lsum; __syncthreads();
    for (int o = 128; o > 0; o >>= 1) { if (t < o) red[t] += red[t + o]; __syncthreads(); }
    float inv = 1.f / red[0];
    for (int j = t; j < NPAD; j += 256) Pr[j] = f2bf(sv[j] * inv);
  } else {
    const float u = 1.f / 4352.f;
    for (int j = t; j < NPAD; j += 256) Pr[j] = f2bf(j >= PAD1 ? u : 0.f);
  }
}

// stage-C a3 softmax over gathered segment of cluster c (bt = c*8+h)
__global__ __launch_bounds__(256) void k_smaxseg(const float* __restrict__ S3, ushort* __restrict__ P3,
                                                 const float* __restrict__ mlandC, const int* __restrict__ gclu,
                                                 const int* __restrict__ segb) {
  int i = blockIdx.x, bt = blockIdx.y, t = threadIdx.x;
  int c = bt >> 3, h = bt & 7;
  const float* Sr = S3 + ((long)h * 256 + i) * NG;
  ushort* Pr = P3 + ((long)h * 256 + i) * NG;
  int jb = segb[c], je = segb[c + 1];
  __shared__ float sv[4352];
  __shared__ float red[256];
  if (mlandC[c * 256 + i] > 0.f) {
    float lmax = NEGV;
    for (int j = jb + t; j < je; j += 256) {
      float s = Sr[j];
      sv[j - jb] = s;
      if (gclu[j] == c) lmax = fmaxf(lmax, s);
    }
    red[t] = lmax; __syncthreads();
    for (int o = 128; o > 0; o >>= 1) { if (t < o) red[t] = fmaxf(red[t], red[t + o]); __syncthreads(); }
    float mx = red[0]; __syncthreads();
    float lsum = 0.f;
    for (int j = jb + t; j < je; j += 256) {
      float e = (gclu[j] == c) ? expf(sv[j - jb] - mx) : 0.f;
      sv[j - jb] = e; lsum += e;
    }
    red[t] = lsum; __syncthreads();
    for (int o = 128; o > 0; o >>= 1) { if (t < o) red[t] += red[t + o]; __syncthreads(); }
    float inv = 1.f / red[0];
    for (int j = jb + t; j < je; j += 256) Pr[j] = f2bf(sv[j - jb] * inv);
  } else {
    const float u = 1.f / 4352.f;
    for (int j = jb + t; j < je; j += 256) Pr[j] = f2bf(gclu[j] == c ? u : 0.f);
  }
}

// 256-col softmax for a1. MODE 0: stage B (mland[j]); MODE 1: stage C gathered rows.
template<int MODE>
__global__ __launch_bounds__(256) void k_smax256(const float* __restrict__ S, ushort* __restrict__ P,
                                                 const float* __restrict__ mland, const int* __restrict__ gtok,
                                                 const int* __restrict__ gclu, int rows) {
  int row = blockIdx.x, h = blockIdx.y, j = threadIdx.x;
  const float* Sr = S + ((long)h * rows + row) * 256;
  ushort* Pr = P + ((long)h * rows + row) * 256;
  int c = 0;
  if (MODE == 1) {
    int tk = gtok[row];
    if (tk < 0) { Pr[j] = 0; return; }
    c = gclu[row];
  }
  bool mem = (MODE == 1) ? (mland[c * 256 + j] > 0.f) : (mland[j] > 0.f);
  __shared__ float red[256];
  float s = mem ? Sr[j] : NEGV;
  red[j] = s; __syncthreads();
  for (int o = 128; o > 0; o >>= 1) { if (j < o) red[j] = fmaxf(red[j], red[j + o]); __syncthreads(); }
  float mx = red[0]; __syncthreads();
  float e = mem ? expf(s - mx) : 0.f;
  red[j] = e; __syncthreads();
  for (int o = 128; o > 0; o >>= 1) { if (j < o) red[j] += red[j + o]; __syncthreads(); }
  Pr[j] = f2bf(e / red[0]);
}

// reduce split-K PV slices -> av bf16 (stage B)
__global__ void k_avredB(const float* __restrict__ sl, ushort* __restrict__ avb, int ks) {
  int i = blockIdx.x, h = blockIdx.y, d = threadIdx.x;
  float s = 0.f;
  for (int k = 0; k < ks; ++k) s += sl[(((long)h * ks + k) * 256 + i) * 64 + d];
  avb[((long)h * 256 + i) * 64 + d] = f2bf(s);
}

__global__ void k_conv_B(const float* __restrict__ qkv, const float* __restrict__ w, float* __restrict__ preout) {
  int prow = PAD1 + blockIdx.x, t = threadIdx.x;
  int h = t >> 6;
  float acc = 0.f;
  for (int tt = 0; tt < 33; ++tt) {
    int p = prow + tt - 16;
    if (p >= 0 && p < NPAD) acc += qkv[(long)p * 1536 + 1024 + t] * w[h * 33 + tt];
  }
  preout[(long)prow * E + t] += acc;
}

__global__ void k_idx(const float* __restrict__ x, int* __restrict__ idx) {
  int n = blockIdx.x;
  const float* tok = x + (long)(9 + n) * E;
  const float* pmt = x + E;
  __shared__ float red[64];
  int t = threadIdx.x;
  int c = t >> 3, part = t & 7;
  float s = 0.f;
  for (int d = part * 64; d < part * 64 + 64; ++d) s += tok[d] * pmt[(long)c * E + d];
  red[t] = s; __syncthreads();
  if (t < 8) {
    float dot = 0.f;
    for (int p = 0; p < 8; ++p) dot += red[t * 8 + p];
    red[t] = dot;
  }
  __syncthreads();
  if (t == 0) {
    int best = 0; float bv = red[0];
    for (int c2 = 1; c2 < 8; ++c2) if (red[c2] > bv) { bv = red[c2]; best = c2; }
    idx[n] = best;
  }
}

__global__ void k_ptc(const float* __restrict__ x, float* __restrict__ ptc_out) {
  int t = threadIdx.x;
  int a = t >> 3, b = t & 7;
  const float* pmt = x + E;
  float s = 0.f;
  for (int d = 0; d < E; ++d) s += pmt[(long)a * E + d] * pmt[(long)b * E + d];
  s -= (a == b) ? 1.f : 0.f;
  __shared__ float red[64];
  red[t] = s * s; __syncthreads();
  for (int o = 32; o > 0; o >>= 1) { if (t < o) red[t] += red[t + o]; __syncthreads(); }
  if (t == 0) *ptc_out = sqrtf(red[0]);
}

__global__ void k_lm_C(const int* __restrict__ idx, float* __restrict__ div_c, float* __restrict__ mland_c) {
  int c = blockIdx.x, i = threadIdx.x;
  int cnt = 0;
  for (int j = 0; j < 17; ++j) {
    int p = i * 17 + j;
    if (p == 255) cnt++;
    else if (p >= 256 && idx[p - 256] == c) cnt++;
  }
  div_c[c * 256 + i] = (float)cnt + 1e-8f;
  mland_c[c * 256 + i] = cnt > 0 ? 1.f : 0.f;
}

__global__ void k_qlkl_C(const float* __restrict__ qkv, const float* __restrict__ qkv_pmt,
                         const int* __restrict__ idx, const float* __restrict__ div_c,
                         ushort* __restrict__ qlc, ushort* __restrict__ klc) {
  int i = blockIdx.x, bt = blockIdx.y;
  int c = bt >> 3, h = bt & 7, d = threadIdx.x;
  float sq = 0.f, sk = 0.f;
  for (int j = 0; j < 17; ++j) {
    int p = i * 17 + j;
    const float* src = nullptr;
    if (p == 255) src = qkv_pmt + c * 1536;
    else if (p >= 256 && idx[p - 256] == c) src = qkv + (long)(p - 256) * 1536;
    if (src) { sq += src[h * 64 + d]; sk += src[512 + h * 64 + d]; }
  }
  float dv = div_c[c * 256 + i];
  qlc[((long)bt * 256 + i) * 64 + d] = f2bf(sq * 0.125f / dv);
  klc[((long)bt * 256 + i) * 64 + d] = f2bf(sk / dv);
}

// ---- gather infrastructure ----
__global__ void k_gcnt(const int* __restrict__ idx, int* __restrict__ scnt) {
  __shared__ int loc[8];
  int b = blockIdx.x, t = threadIdx.x;
  if (t < 8) loc[t] = 0;
  __syncthreads();
  atomicAdd(&loc[idx[b * 256 + t]], 1);
  __syncthreads();
  if (t < 8) scnt[t * 16 + b] = loc[t];
}

__global__ void k_goff(const int* __restrict__ scnt, int* __restrict__ segb, int* __restrict__ boff,
                       int* __restrict__ krange, int* __restrict__ blkclu,
                       int* __restrict__ gtok, int* __restrict__ gclu) {
  if (threadIdx.x != 0) return;
  int s = 0;
  for (int c = 0; c < 8; ++c) {
    segb[c] = s;
    int tot = 1;
    int run = s + 1;
    for (int sl = 0; sl < 16; ++sl) { boff[c * 16 + sl] = run; run += scnt[c * 16 + sl]; tot += scnt[c * 16 + sl]; }
    krange[2 * c] = s;
    krange[2 * c + 1] = s + (((tot + 31) >> 5) << 5);
    gtok[s] = -2 - c; gclu[s] = c;
    s += ((tot + 127) >> 7) << 7;
  }
  segb[8] = s;
  for (int b = 0; b < NG / 128; ++b) {
    int cl = -1;
    for (int c = 0; c < 8; ++c) if (b * 128 >= segb[c] && b * 128 < segb[c + 1]) cl = c;
    blkclu[b] = cl;
  }
}

__global__ void k_gscatter(const int* __restrict__ idx, const int* __restrict__ boff,
                           int* __restrict__ gtok, int* __restrict__ gclu, int* __restrict__ gpos) {
  __shared__ int sidx[256];
  int b = blockIdx.x, t = threadIdx.x;
  int n = b * 256 + t;
  int c = idx[n];
  sidx[t] = c;
  __syncthreads();
  int rank = 0;
  for (int m = 0; m < t; ++m) rank += (sidx[m] == c);
  int pos = boff[c * 16 + b] + rank;
  gtok[pos] = n; gclu[pos] = c; gpos[n] = pos;
}

__global__ void k_gatherQK(const float* __restrict__ qkv, const float* __restrict__ qkv_pmt,
                           const int* __restrict__ gtok, ushort* __restrict__ Qg, ushort* __restrict__ Kg) {
  long i = (long)blockIdx.x * 256 + threadIdx.x;
  if (i >= (long)NG * 512) return;
  int g = (int)(i >> 9), t = (int)(i & 511); int h = t >> 6, d = t & 63;
  int tk = gtok[g];
  float q = 0.f, k = 0.f;
  if (tk >= 0)       { q = qkv[(long)tk * 1536 + t];      k = qkv[(long)tk * 1536 + 512 + t]; }
  else if (tk <= -2) { int c = -2 - tk; q = qkv_pmt[c * 1536 + t]; k = qkv_pmt[c * 1536 + 512 + t]; }
  long o = ((long)h * NG + g) * 64 + d;
  Qg[o] = f2bf(q); Kg[o] = f2bf(k);
}

__global__ void k_gatherVt(const float* __restrict__ qkv, const float* __restrict__ qkv_pmt,
                           const int* __restrict__ gtok, ushort* __restrict__ Vgt) {
  int h = blockIdx.y, p0 = blockIdx.x * 64;
  __shared__ float tile[64][65];
  int tx = threadIdx.x & 63, tg = threadIdx.x >> 6;
  for (int r = tg; r < 64; r += 4) {
    int tk = gtok[p0 + r];
    float v = 0.f;
    if (tk >= 0)       v = qkv[(long)tk * 1536 + 1024 + h * 64 + tx];
    else if (tk <= -2) v = qkv_pmt[(-2 - tk) * 1536 + 1024 + h * 64 + tx];
    tile[r][tx] = v;
  }
  __syncthreads();
  for (int d = tg; d < 64; d += 4) Vgt[((long)h * 64 + d) * NG + p0 + tx] = f2bf(tile[tx][d]);
}

// scatter gathered a1 output + depthwise conv -> OUTA
__global__ void k_outC(const float* __restrict__ OUTg, const int* __restrict__ gpos,
                       const int* __restrict__ idx, const float* __restrict__ qkv,
                       const float* __restrict__ qkv_pmt, const float* __restrict__ w,
                       float* __restrict__ OUTA) {
  int n = blockIdx.x, t = threadIdx.x;   // 512
  int h = t >> 6;
  int c = idx[n];
  float acc = OUTg[(long)gpos[n] * 512 + t];
  for (int tt = 0; tt < 33; ++tt) {
    int m = n + tt - 16;
    float vv = 0.f;
    if (m == -1) vv = qkv_pmt[c * 1536 + 1024 + t];
    else if (m >= 0 && m < NTOK && idx[m] == c) vv = qkv[(long)m * 1536 + 1024 + t];
    acc += vv * w[h * 33 + tt];
  }
  OUTA[(long)n * E + t] = acc;
}

__global__ void k_seg_part(const float* __restrict__ hun, const int* __restrict__ idx,
                           float* __restrict__ part, float* __restrict__ pcnt) {
  int c = blockIdx.x, sl = blockIdx.y, d = threadIdx.x;
  float s = 0.f; int cnt = 0;
  for (int n = sl * 256; n < sl * 256 + 256; ++n) {
    if (idx[n] == c) { s += hun[(long)n * E + d]; if (d == 0) cnt++; }
  }
  part[(long)(c * 16 + sl) * E + d] = s;
  if (d == 0) pcnt[c * 16 + sl] = (float)cnt;
}

__global__ void k_final(const float* __restrict__ x0, const float* __restrict__ g, const float* __restrict__ b,
                        const float* __restrict__ part, const float* __restrict__ pcnt,
                        const float* __restrict__ ptc, const float* __restrict__ W3, const float* __restrict__ b3,
                        float* __restrict__ out) {
  int t = threadIdx.x;
  __shared__ float red[512];
  float xv = x0[t];
  red[t] = xv; __syncthreads();
  for (int o = 256; o > 0; o >>= 1) { if (t < o) red[t] += red[t + o]; __syncthreads(); }
  float mu = red[0] * (1.f / 512.f); __syncthreads();
  float d0 = xv - mu;
  red[t] = d0 * d0; __syncthreads();
  for (int o = 256; o > 0; o >>= 1) { if (t < o) red[t] += red[t + o]; __syncthreads(); }
  float inv = 1.f / sqrtf(red[0] * (1.f / 512.f) + 1e-5f);
  __syncthreads();
  float acc = d0 * inv * g[t] + b[t];
  for (int c = 0; c < 8; ++c) {
    float s = 0.f, cnt = 0.f;
    for (int sl = 0; sl < 16; ++sl) { s += part[(long)(c * 16 + sl) * E + t]; cnt += pcnt[c * 16 + sl]; }
    acc += s / fmaxf(cnt, 1.f);
  }
  float tk = acc * (1.f / 9.f);
  red[t] = tk * W3[t * 2 + 0]; __syncthreads();
  for (int o = 256; o > 0; o >>= 1) { if (t < o) red[t] += red[t + o]; __syncthreads(); }
  float l0 = red[0] + b3[0]; __syncthreads();
  red[t] = tk * W3[t * 2 + 1]; __syncthreads();
  for (int o = 256; o > 0; o >>= 1) { if (t < o) red[t] += red[t + o]; __syncthreads(); }
  float l1 = red[0] + b3[1];
  if (t == 0) {
    out[0] = l0; out[1] = l1;
    float mx = fmaxf(l0, l1);
    float e0 = expf(l0 - mx), e1 = expf(l1 - mx), s = e0 + e1;
    out[2] = e0 / s; out[3] = e1 / s;
    out[4] = *ptc;
  }
}

// 6 Newton-Schulz iterations, bf16 GEMMs, aI-B folded into NN staging (flag 4)
static void pinv_iters(hipStream_t st, const ushort* PX, ushort* PZ, ushort* Y, ushort* T1, ushort* T2, int nb) {
  ushort* z = PZ; ushort* y = Y;
  for (int it = 0; it < 6; ++it) {
    mm(st, PX, z,  nullptr, nullptr, nullptr, y,  256,256,256, nb,1,256, 65536,65536,65536, nullptr,nullptr,0,0,nullptr,0, 1.f,   0.f, 16,    false, false);
    mm(st, y,  y,  nullptr, nullptr, nullptr, T1, 256,256,256, nb,1,256, 65536,65536,65536, nullptr,nullptr,0,0,nullptr,0, 1.f,   7.f, 16|4,  false, false);
    mm(st, y,  T1, nullptr, nullptr, nullptr, T2, 256,256,256, nb,1,256, 65536,65536,65536, nullptr,nullptr,0,0,nullptr,0, 1.f,  15.f, 16|4,  false, false);
    mm(st, z,  T2, nullptr, nullptr, nullptr, y,  256,256,256, nb,1,256, 65536,65536,65536, nullptr,nullptr,0,0,nullptr,0, 0.25f,13.f, 16|4,  false, false);
    ushort* tmp = z; z = y; y = tmp;
  }  // 6 swaps -> z == PZ
}

// ================= host =================
extern "C" void kernel_launch(void* const* d_in, const int* in_sizes, int n_in,
                              void* d_out, int out_size, void* d_ws, size_t ws_size,
                              hipStream_t stream) {
  const float* h_in  = (const float*)d_in[0];
  const float* W1    = (const float*)d_in[1];
  const float* b1    = (const float*)d_in[2];
  const float* cls   = (const float*)d_in[3];
  const float* pmt_t = (const float*)d_in[4];
  const float* ln1_g = (const float*)d_in[5];
  const float* ln1_b = (const float*)d_in[6];
  const float* Wqkv1 = (const float*)d_in[7];
  const float* Wout1 = (const float*)d_in[8];
  const float* bout1 = (const float*)d_in[9];
  const float* conv1 = (const float*)d_in[10];
  const float* ln0_g = (const float*)d_in[11];
  const float* ln0_b = (const float*)d_in[12];
  const float* Wqkv0 = (const float*)d_in[13];
  const float* Wout0 = (const float*)d_in[14];
  const float* bout0 = (const float*)d_in[15];
  const float* conv0 = (const float*)d_in[16];
  const float* lnf_g = (const float*)d_in[17];
  const float* lnf_b = (const float*)d_in[18];
  const float* W3    = (const float*)d_in[19];
  const float* b3    = (const float*)d_in[20];

  char* base = (char*)d_ws;
  size_t off = 0;
  auto alloc = [&](size_t b) -> void* {
    off = (off + 255) & ~(size_t)255;
    void* p = base + off; off += b; return p;
  };
  float*  SEQ    = (float*) alloc((size_t)NSEQ * E * 4);
  float*  QKV    = (float*) alloc((size_t)NPAD * 1536 * 4);
  float*  QKVPMT = (float*) alloc(8 * 1536 * 4);
  ushort* W1t    = (ushort*)alloc((size_t)512 * 1024 * 2);
  ushort* Wq1t   = (ushort*)alloc((size_t)1536 * 512 * 2);
  ushort* Wq0t   = (ushort*)alloc((size_t)1536 * 512 * 2);
  ushort* Wo1t   = (ushort*)alloc((size_t)512 * 512 * 2);
  ushort* Wo0t   = (ushort*)alloc((size_t)512 * 512 * 2);
  ushort* LNb    = (ushort*)alloc((size_t)NPAD * E * 2);
  ushort* LNPMTb = (ushort*)alloc(8 * 512 * 2);
  ushort* QbU    = (ushort*)alloc((size_t)8 * NG * 64 * 2);   // Qb (B) / Qg (C)
  ushort* KbU    = (ushort*)alloc((size_t)8 * NG * 64 * 2);   // Kb (B) / Kg (C)
  ushort* VtU    = (ushort*)alloc((size_t)8 * NG * 64 * 2);   // Vtb (B) / Vgt (C)
  char*   U1     = (char*)  alloc((size_t)8 * 256 * NG * 4);  // 41.9 MB scratch (scores / pinv temps / OUTg / hb)
  char*   U2     = (char*)  alloc((size_t)8 * 256 * NG * 2);  // 21 MB (P matrices)
  ushort* PXb    = (ushort*)alloc((size_t)64 * 65536 * 2);
  ushort* PZa    = (ushort*)alloc((size_t)64 * 65536 * 2);
  ushort* qlbB   = (ushort*)alloc((size_t)8 * 16384 * 2);
  ushort* klbB   = (ushort*)alloc((size_t)8 * 16384 * 2);
  ushort* qlcb   = (ushort*)alloc((size_t)64 * 16384 * 2);
  ushort* klcb   = (ushort*)alloc((size_t)64 * 16384 * 2);
  float*  avsl   = (float*) alloc((size_t)8 * 8 * 16384 * 4);
  ushort* avb    = (ushort*)alloc((size_t)64 * 16384 * 2);
  ushort* Wcb    = (ushort*)alloc((size_t)64 * 16384 * 2);
  float*  PREOUT = (float*) alloc((size_t)NPAD * E * 4);
  float*  OUTA   = (float*) alloc((size_t)NTOK * E * 4);
  float*  divB   = (float*) alloc(256 * 4);
  float*  mlandB = (float*) alloc(256 * 4);
  float*  divC   = (float*) alloc(8 * 256 * 4);
  float*  mlandC = (float*) alloc(8 * 256 * 4);
  int*    idx    = (int*)   alloc(NTOK * 4);
  int*    gtok   = (int*)   alloc(NG * 4);
  int*    gclu   = (int*)   alloc(NG * 4);
  int*    gpos   = (int*)   alloc(NTOK * 4);
  int*    scnt   = (int*)   alloc(8 * 16 * 4);
  int*    boffA  = (int*)   alloc(8 * 16 * 4);
  int*    segb   = (int*)   alloc(9 * 4);
  int*    krange = (int*)   alloc(16 * 4);
  int*    blkclu = (int*)   alloc((NG / 128) * 4);
  float*  ptc    = (float*) alloc(256);
  float*  sc     = (float*) alloc(256);
  float*  part   = (float*) alloc((size_t)8 * 16 * 512 * 4);
  float*  pcnt   = (float*) alloc(8 * 16 * 4);

  // U1 overlays
  ushort* hb   = (ushort*)U1;                             // stage-A bf16 input
  float*  Sbuf = (float*)U1;                              // all score matrices
  ushort* Ybuf = (ushort*)U1;                             // pinv temps
  ushort* T1   = (ushort*)(U1 + (size_t)64 * 65536 * 2);
  ushort* T2   = (ushort*)(U1 + (size_t)2 * 64 * 65536 * 2);
  float*  OUTg = (float*)U1;                              // gathered a1C output
  // U2 overlays
  ushort* Pbuf = (ushort*)U2;                             // Pav / P1B / P3 / P1C

  // -------- weight conversions --------
  k_tcvt<<<dim3(512/32, 1024/32), dim3(32,8), 0, stream>>>(W1, W1t, 1024, 512);
  k_tcvt<<<dim3(1536/32, 512/32), dim3(32,8), 0, stream>>>(Wqkv1, Wq1t, 512, 1536);
  k_tcvt<<<dim3(1536/32, 512/32), dim3(32,8), 0, stream>>>(Wqkv0, Wq0t, 512, 1536);
  k_tcvt<<<dim3(512/32, 512/32),  dim3(32,8), 0, stream>>>(Wout1, Wo1t, 512, 512);
  k_tcvt<<<dim3(512/32, 512/32),  dim3(32,8), 0, stream>>>(Wout0, Wo0t, 512, 512);

  // ======== Stage A ========
  k_copy<<<dim3(2),  dim3(256), 0, stream>>>(cls,   SEQ,       512);
  k_copy<<<dim3(16), dim3(256), 0, stream>>>(pmt_t, SEQ + 512, 4096);
  k_cvt<<<dim3(16384), dim3(256), 0, stream>>>(h_in, hb, (long)4096 * 1024);
  mm(stream, hb, W1t, b1, nullptr, SEQ + 9 * 512, nullptr, 4096, 512, 1024, 1, 1, 512,
     0, 0, 0, nullptr, nullptr, 0, 0, nullptr, 0, 1.f, 0.f, 1 | 2, true, false);

  // ======== Stage B ========
  hipMemsetAsync(LNb, 0, (size_t)PAD1 * E * 2, stream);
  k_ln<<<dim3(NSEQ), dim3(256), 0, stream>>>(SEQ, ln1_g, ln1_b, LNb + (long)PAD1 * E, NSEQ);
  mm(stream, LNb, Wq1t, nullptr, nullptr, QKV, nullptr, NPAD, 1536, 512, 1, 1, 1536,
     0, 0, 0, nullptr, nullptr, 0, 0, nullptr, 0, 1.f, 0.f, 0, true, false);
  k_buildK<<<dim3((NPAD*512)/256), dim3(256), 0, stream>>>(QKV, QbU, NPAD, 0);
  k_buildK<<<dim3((NPAD*512)/256), dim3(256), 0, stream>>>(QKV, KbU, NPAD, 512);
  k_buildVt<<<dim3(NPAD/64, 8), dim3(256), 0, stream>>>(QKV, VtU, NPAD);
  k_lm_B<<<dim3(1), dim3(256), 0, stream>>>(divB, mlandB);
  k_qlkl_B<<<dim3(256, 8), dim3(64), 0, stream>>>(QKV, divB, qlbB, klbB);
  // a2 + pinv
  mm(stream, qlbB, klbB, nullptr, nullptr, Sbuf, nullptr, 256, 256, 64, 8, 1, 256,
     16384, 16384, 65536, nullptr, nullptr, 0, 0, nullptr, 0, 1.f, 0.f, 0, true, false);
  k_a2soft<<<dim3(256, 8), dim3(256), 0, stream>>>(Sbuf, mlandB, PXb);
  k_pinv_scale<<<dim3(1), dim3(256), 0, stream>>>(PXb, sc, 8);
  k_z0<<<dim3((8*65536)/256), dim3(256), 0, stream>>>(PXb, sc, PZa, 8);
  pinv_iters(stream, PXb, PZa, Ybuf, T1, T2, 8);
  // a3 @ v
  mm(stream, qlbB, KbU, nullptr, nullptr, Sbuf, nullptr, 256, NPAD, 64, 8, 1, NPAD,
     16384, (long)NPAD*64, (long)256*NPAD, nullptr, nullptr, 0, 0, nullptr, 0, 1.f, 0.f, 0, true, false);
  k_smaxB_av<<<dim3(256, 8), dim3(256), 0, stream>>>(Sbuf, Pbuf, mlandB);
  mm(stream, Pbuf, VtU, nullptr, nullptr, avsl, nullptr, 256, 64, NPAD, 8, 8, 64,
     (long)256*NPAD, (long)64*NPAD, 16384, nullptr, nullptr, 0, 0, nullptr, 0, 1.f, 0.f, 0, true, true);
  k_avredB<<<dim3(256, 8), dim3(64), 0, stream>>>(avsl, avb, 8);
  // W = Z @ av
  mm(stream, PZa, avb, nullptr, nullptr, nullptr, Wcb, 256, 64, 256, 8, 1, 64,
     65536, 16384, 16384, nullptr, nullptr, 0, 0, nullptr, 0, 1.f, 0.f, 16, false, true);
  // a1: scores -> softmax -> @W
  mm(stream, QbU + PAD1*64, klbB, nullptr, nullptr, Sbuf, nullptr, NSEQ, 256, 64, 8, 1, 256,
     (long)NPAD*64, 16384, (long)NSEQ*256, nullptr, nullptr, 0, 0, nullptr, 0, 0.125f, 0.f, 0, true, true);
  k_smax256<0><<<dim3(NSEQ, 8), dim3(256), 0, stream>>>(Sbuf, Pbuf, mlandB, nullptr, nullptr, NSEQ);
  mm(stream, Pbuf, Wcb, nullptr, nullptr, PREOUT + (long)PAD1*512, nullptr, NSEQ, 64, 256, 8, 1, 512,
     (long)NSEQ*256, 16384, 64, nullptr, nullptr, 0, 0, nullptr, 0, 1.f, 0.f, 0, false, true);
  k_conv_B<<<dim3(NSEQ), dim3(512), 0, stream>>>(QKV, conv1, PREOUT);
  k_cvt<<<dim3((NSEQ*512 + 255)/256), dim3(256), 0, stream>>>(PREOUT + (long)PAD1*E, LNb, (long)NSEQ * 512);
  mm(stream, LNb, Wo1t, bout1, SEQ, SEQ, nullptr, NSEQ, 512, 512, 1, 1, 512,
     0, 0, 0, nullptr, nullptr, 0, 0, nullptr, 0, 1.f, 0.f, 1 | 8, true, true);   // x = seq + y

  // ======== Stage C ========
  k_idx<<<dim3(NTOK), dim3(64), 0, stream>>>(SEQ, idx);
  k_ptc<<<dim3(1), dim3(64), 0, stream>>>(SEQ, ptc);
  hipMemsetAsync(gtok, 0xFF, NG * 4, stream);
  hipMemsetAsync(gclu, 0xFF, NG * 4, stream);
  k_gcnt<<<dim3(16), dim3(256), 0, stream>>>(idx, scnt);
  k_goff<<<dim3(1), dim3(64), 0, stream>>>(scnt, segb, boffA, krange, blkclu, gtok, gclu);
  k_gscatter<<<dim3(16), dim3(256), 0, stream>>>(idx, boffA, gtok, gclu, gpos);
  k_ln<<<dim3(NTOK), dim3(256), 0, stream>>>(SEQ + 9 * 512, ln0_g, ln0_b, LNb, NTOK);
  k_ln<<<dim3(8), dim3(256), 0, stream>>>(SEQ + 512, ln0_g, ln0_b, LNPMTb, 8);
  mm(stream, LNb, Wq0t, nullptr, nullptr, QKV, nullptr, NTOK, 1536, 512, 1, 1, 1536,
     0, 0, 0, nullptr, nullptr, 0, 0, nullptr, 0, 1.f, 0.f, 0, true, false);
  mm(stream, LNPMTb, Wq0t, nullptr, nullptr, QKVPMT, nullptr, 8, 1536, 512, 1, 1, 1536,
     0, 0, 0, nullptr, nullptr, 0, 0, nullptr, 0, 1.f, 0.f, 0, true, true);
  k_lm_C<<<dim3(8), dim3(256), 0, stream>>>(idx, divC, mlandC);
  k_qlkl_C<<<dim3(256, 64), dim3(64), 0, stream>>>(QKV, QKVPMT, idx, divC, qlcb, klcb);
  k_gatherQK<<<dim3((NG*512)/256), dim3(256), 0, stream>>>(QKV, QKVPMT, gtok, QbU, KbU);
  k_gatherVt<<<dim3(NG/64, 8), dim3(256), 0, stream>>>(QKV, QKVPMT, gtok, VtU);
  // a2 + pinv
  mm(stream, qlcb, klcb, nullptr, nullptr, Sbuf, nullptr, 256, 256, 64, 64, 1, 256,
     16384, 16384, 65536, nullptr, nullptr, 0, 0, nullptr, 0, 1.f, 0.f, 0, true, false);
  k_a2soft<<<dim3(256, 64), dim3(256), 0, stream>>>(Sbuf, mlandC, PXb);
  k_pinv_scale<<<dim3(8), dim3(256), 0, stream>>>(PXb, sc, 8);
  k_z0<<<dim3((64*65536)/256), dim3(256), 0, stream>>>(PXb, sc, PZa, 64);
  pinv_iters(stream, PXb, PZa, Ybuf, T1, T2, 64);
  // a3 @ v (gathered): S3[h][256][NG], A selected by column-block cluster
  mm(stream, qlcb, KbU, nullptr, nullptr, Sbuf, nullptr, 256, NG, 64, 8, 1, NG,
     16384, (long)NG*64, (long)256*NG, blkclu, nullptr, 0, 0, nullptr, 0, 1.f, 0.f, 0, true, false);
  k_smaxseg<<<dim3(256, 64), dim3(256), 0, stream>>>(Sbuf, Pbuf, mlandC, gclu, segb);
  mm(stream, Pbuf, VtU, nullptr, nullptr, nullptr, avb, 256, 64, NG, 64, 1, 64,
     (long)256*NG, (long)64*NG, 16384, nullptr, nullptr, 8, 8, krange, 3, 1.f, 0.f, 16, true, true);
  // W = Z @ av
  mm(stream, PZa, avb, nullptr, nullptr, nullptr, Wcb, 256, 64, 256, 64, 1, 64,
     65536, 16384, 16384, nullptr, nullptr, 0, 0, nullptr, 0, 1.f, 0.f, 16, false, true);
  // a1 (gathered rows): scores -> softmax -> @W -> scatter+conv
  mm(stream, QbU, klcb, nullptr, nullptr, Sbuf, nullptr, NG, 256, 64, 8, 1, 256,
     (long)NG*64, 16384, (long)NG*256, nullptr, blkclu, 0, 0, nullptr, 0, 0.125f, 0.f, 0, true, false);
  k_smax256<1><<<dim3(NG, 8), dim3(256), 0, stream>>>(Sbuf, Pbuf, mlandC, gtok, gclu, NG);
  mm(stream, Pbuf, Wcb, nullptr, nullptr, OUTg, nullptr, NG, 64, 256, 8, 1, 512,
     (long)NG*256, 16384, 64, nullptr, blkclu, 0, 0, nullptr, 0, 1.f, 0.f, 0, false, true);
  k_outC<<<dim3(NTOK), dim3(512), 0, stream>>>(OUTg, gpos, idx, QKV, QKVPMT, conv0, OUTA);
  k_cvt<<<dim3((NTOK*512)/256), dim3(256), 0, stream>>>(OUTA, LNb, (long)NTOK * 512);
  mm(stream, LNb, Wo0t, bout0, SEQ + 9 * 512, PREOUT, nullptr, NTOK, 512, 512, 1, 1, 512,
     0, 0, 0, nullptr, nullptr, 0, 0, nullptr, 0, 1.f, 0.f, 1 | 8, true, false);   // h_un

  // ======== Final ========
  k_seg_part<<<dim3(8, 16), dim3(512), 0, stream>>>(PREOUT, idx, part, pcnt);
  k_final<<<dim3(1), dim3(512), 0, stream>>>(SEQ, lnf_g, lnf_b, part, pcnt, ptc, W3, b3,
                                             (float*)d_out);
}

// Round 4
// 2513.361 us; speedup vs baseline: 2.6762x; 1.0791x over previous
//
#include <hip/hip_runtime.h>

#define NEGV (-1.70141173e38f)   // -finfo(f32).max / 2, matches jnp mask fill

constexpr int E    = 512;
constexpr int NTOK = 4096;
constexpr int NPAD = 4352;
constexpr int PAD1 = 247;
constexpr int NSEQ = 4105;
constexpr int NG   = 5120;   // gathered slots (8 clusters, 128-aligned segments)
constexpr int NTP  = 4104;   // stage-C LN/QKV rows: 8 pmt + 4096 tokens

typedef __attribute__((ext_vector_type(8))) short short8;
typedef __attribute__((ext_vector_type(4))) float float4v;

__device__ inline float bf2f(ushort u){ return __uint_as_float(((unsigned)u)<<16); }
__device__ inline ushort f2bf(float f){
  unsigned u = __float_as_uint(f);
  unsigned r = (u + 0x7FFFu + ((u>>16)&1u)) >> 16;   // RNE
  return (ushort)r;
}
__device__ inline short8 pack8u(const ushort* u) {
  union { short8 v; unsigned w[4]; } x;
  x.w[0] = (unsigned)u[0] | ((unsigned)u[1] << 16);
  x.w[1] = (unsigned)u[2] | ((unsigned)u[3] << 16);
  x.w[2] = (unsigned)u[4] | ((unsigned)u[5] << 16);
  x.w[3] = (unsigned)u[6] | ((unsigned)u[7] << 16);
  return x.v;
}

// ================= bf16 MFMA GEMM (unchanged from round 3, verified) =================
template<int BT, bool BOUNDS>
__global__ __launch_bounds__(256) void k_mm(
    const ushort* __restrict__ A, const ushort* __restrict__ B,
    const float* __restrict__ bias, const float* __restrict__ resid,
    float* __restrict__ Cf, ushort* __restrict__ Cb,
    int M, int N, int K, int ksplit, int ldC,
    long sA, long sB, long sC,
    const int* __restrict__ colsel, const int* __restrict__ rowsel,
    int zmodA, int zmodB, const int* __restrict__ krange, int kshift,
    float alpha, float bdiag, int flags)
{
  const int z = blockIdx.z;
  const int batch = z / ksplit, ks = z - batch * ksplit;
  const int kslice = K / ksplit;
  int kbeg = ks * kslice, kend = kbeg + kslice;
  if (krange) { int ki = batch >> kshift; kbeg = krange[2*ki]; kend = krange[2*ki+1]; }
  long aoff;
  if (colsel) { int s = colsel[blockIdx.x]; if (s < 0) s = 0; aoff = (long)(s*8 + batch) * sA; }
  else aoff = (long)(zmodA ? (batch & (zmodA-1)) : batch) * sA;
  long boff;
  if (rowsel) { int s = rowsel[blockIdx.y]; if (s < 0) s = 0; boff = (long)(s*8 + batch) * sB; }
  else boff = (long)(zmodB ? (batch & (zmodB-1)) : batch) * sB;
  A += aoff; B += boff;
  const long coff = (long)z * sC;

  __shared__ __align__(16) ushort Al[4][128][8];
  __shared__ __align__(16) ushort Bl[4][128][8];

  const int tid  = threadIdx.x;
  const int lane = tid & 63, wid = tid >> 6;
  const int wr = wid >> 1, wc = wid & 1;
  const int l4 = lane >> 4, l15 = lane & 15;
  const int row0 = blockIdx.y * 128, col0 = blockIdx.x * 128;

  float4v acc[4][4];
#pragma unroll
  for (int i = 0; i < 4; ++i)
#pragma unroll
    for (int j = 0; j < 4; ++j) acc[i][j] = (float4v){0.f,0.f,0.f,0.f};

  for (int k0 = kbeg; k0 < kend; k0 += 32) {
    __syncthreads();
#pragma unroll
    for (int e = 0; e < 2; ++e) {
      int id = tid * 2 + e; int m = id >> 2, kb = id & 3;
      uint4 v = make_uint4(0u,0u,0u,0u);
      int gr = row0 + m;
      if (!BOUNDS || gr < M)
        v = *reinterpret_cast<const uint4*>(A + (long)gr * K + k0 + kb * 8);
      *reinterpret_cast<uint4*>(&Al[kb][m][0]) = v;
    }
    if (BT) {
#pragma unroll
      for (int e = 0; e < 2; ++e) {
        int id = tid * 2 + e; int n = id >> 2, kb = id & 3;
        uint4 v = make_uint4(0u,0u,0u,0u);
        int gc = col0 + n;
        if (!BOUNDS || gc < N)
          v = *reinterpret_cast<const uint4*>(B + (long)gc * K + k0 + kb * 8);
        *reinterpret_cast<uint4*>(&Bl[kb][n][0]) = v;
      }
    } else {
      int n = tid & 127, gc = col0 + n;
      bool inb = (!BOUNDS || gc < N);
#pragma unroll
      for (int e = 0; e < 2; ++e) {
        int kb = (tid >> 7) * 2 + e;
        ushort u[8];
#pragma unroll
        for (int j = 0; j < 8; ++j) {
          int gk = k0 + kb * 8 + j;
          ushort val = inb ? B[(long)gk * N + gc] : (ushort)0;
          if (flags & 4) {
            float f = bdiag * (gk == gc ? 1.f : 0.f) - bf2f(val);
            val = f2bf(f);
          }
          u[j] = val;
        }
        uint4 w;
        w.x = (unsigned)u[0] | ((unsigned)u[1] << 16);
        w.y = (unsigned)u[2] | ((unsigned)u[3] << 16);
        w.z = (unsigned)u[4] | ((unsigned)u[5] << 16);
        w.w = (unsigned)u[6] | ((unsigned)u[7] << 16);
        *reinterpret_cast<uint4*>(&Bl[kb][n][0]) = w;
      }
    }
    __syncthreads();
    short8 af[4], bg[4];
#pragma unroll
    for (int mi = 0; mi < 4; ++mi)
      af[mi] = *reinterpret_cast<const short8*>(&Al[l4][wr*64 + mi*16 + l15][0]);
#pragma unroll
    for (int ni = 0; ni < 4; ++ni)
      bg[ni] = *reinterpret_cast<const short8*>(&Bl[l4][wc*64 + ni*16 + l15][0]);
#pragma unroll
    for (int mi = 0; mi < 4; ++mi)
#pragma unroll
      for (int ni = 0; ni < 4; ++ni)
        acc[mi][ni] = __builtin_amdgcn_mfma_f32_16x16x32_bf16(af[mi], bg[ni], acc[mi][ni], 0, 0, 0);
  }
#pragma unroll
  for (int mi = 0; mi < 4; ++mi)
#pragma unroll
    for (int ni = 0; ni < 4; ++ni)
#pragma unroll
      for (int r = 0; r < 4; ++r) {
        int row = row0 + wr*64 + mi*16 + l4*4 + r;
        int col = col0 + wc*64 + ni*16 + l15;
        if (BOUNDS && (row >= M || col >= N)) continue;
        float v = alpha * acc[mi][ni][r];
        if (flags & 1) v += bias[col];
        if (flags & 2) v = fmaxf(v, 0.f);
        if (flags & 8) v += resid[(long)row * ldC + col];
        long off = coff + (long)row * ldC + col;
        if (flags & 16) Cb[off] = f2bf(v); else Cf[off] = v;
      }
}

static void mm(hipStream_t st, const void* A, const void* B, const float* bias, const float* resid,
               float* Cf, ushort* Cb, int M, int N, int K, int nb, int ksplit, int ldC,
               long sA, long sB, long sC,
               const int* colsel, const int* rowsel, int zmodA, int zmodB,
               const int* krange, int kshift,
               float alpha, float bdiag, int flags, bool bt, bool bounds)
{
  dim3 g((N + 127) / 128, (M + 127) / 128, nb * ksplit), b(256);
  const ushort* a = (const ushort*)A; const ushort* bb = (const ushort*)B;
  if (bt) {
    if (bounds) k_mm<1, true ><<<g, b, 0, st>>>(a, bb, bias, resid, Cf, Cb, M, N, K, ksplit, ldC, sA, sB, sC, colsel, rowsel, zmodA, zmodB, krange, kshift, alpha, bdiag, flags);
    else        k_mm<1, false><<<g, b, 0, st>>>(a, bb, bias, resid, Cf, Cb, M, N, K, ksplit, ldC, sA, sB, sC, colsel, rowsel, zmodA, zmodB, krange, kshift, alpha, bdiag, flags);
  } else {
    if (bounds) k_mm<0, true ><<<g, b, 0, st>>>(a, bb, bias, resid, Cf, Cb, M, N, K, ksplit, ldC, sA, sB, sC, colsel, rowsel, zmodA, zmodB, krange, kshift, alpha, bdiag, flags);
    else        k_mm<0, false><<<g, b, 0, st>>>(a, bb, bias, resid, Cf, Cb, M, N, K, ksplit, ldC, sA, sB, sC, colsel, rowsel, zmodA, zmodB, krange, kshift, alpha, bdiag, flags);
  }
}

// ================= fused Newton-Schulz pinv chain =================
// One WG per 256x256 batch matrix. Y kept in LDS (XOR-swizzled).
// Iter: Y = X@Z; T1 = 7Y - Y@Y; T2 = 15Y - Y@T1; Zn = 0.25*(13Z - Z@T2).
__device__ __forceinline__ void gsync() {
  __threadfence();
  __syncthreads();
}

template<int AMODE, int BMODE>   // A: 0 global, 1 LDS Y ; B: 0 global (staged), 1 LDS Y
__device__ __forceinline__ void wg_gemm256(
    const ushort* __restrict__ Ag, const ushort* __restrict__ Bg,
    ushort (* __restrict__ Yl)[256], ushort (* __restrict__ Btl)[256],
    float4v acc[8][4], int tid)
{
  const int lane = tid & 63;
  const int wid  = tid >> 6;
  const int wr = wid >> 2, wc = wid & 3;
  const int l4 = lane >> 4, l15 = lane & 15;
#pragma unroll 1
  for (int kt = 0; kt < 8; ++kt) {
    const int k0 = kt * 32;
    if (BMODE == 0) {
      __syncthreads();
      int kk = tid >> 4, n0 = (tid & 15) * 16;
      int s = (kk >> 3) << 4;
      const ushort* src = Bg + (long)(k0 + kk) * 256 + n0;
      *reinterpret_cast<uint4*>(&Btl[kk][n0 ^ s])       = *reinterpret_cast<const uint4*>(src);
      *reinterpret_cast<uint4*>(&Btl[kk][(n0 + 8) ^ s]) = *reinterpret_cast<const uint4*>(src + 8);
      __syncthreads();
    }
    short8 af[8];
#pragma unroll
    for (int mi = 0; mi < 8; ++mi) {
      int r = wr * 128 + mi * 16 + l15;
      if (AMODE == 0) {
        af[mi] = *reinterpret_cast<const short8*>(Ag + (long)r * 256 + k0 + l4 * 8);
      } else {
        int sr = ((r >> 3) & 3) << 4;
        af[mi] = *reinterpret_cast<const short8*>(&Yl[r][(k0 + l4 * 8) ^ sr]);
      }
    }
    short8 bf[4];
#pragma unroll
    for (int ni = 0; ni < 4; ++ni) {
      int c = wc * 64 + ni * 16 + l15;
      ushort u[8];
      if (BMODE == 0) {
        int kb = l4 * 8;
        int cc = c ^ ((kb >> 3) << 4);
#pragma unroll
        for (int j = 0; j < 8; ++j) u[j] = Btl[kb + j][cc];
      } else {
        int kb = k0 + l4 * 8;
        int cc = c ^ (((kb >> 3) & 3) << 4);
#pragma unroll
        for (int j = 0; j < 8; ++j) u[j] = Yl[kb + j][cc];
      }
      bf[ni] = pack8u(u);
    }
#pragma unroll
    for (int mi = 0; mi < 8; ++mi)
#pragma unroll
      for (int ni = 0; ni < 4; ++ni)
        acc[mi][ni] = __builtin_amdgcn_mfma_f32_16x16x32_bf16(af[mi], bf[ni], acc[mi][ni], 0, 0, 0);
  }
}

__global__ __launch_bounds__(512) void k_pinv_chain(
    const ushort* __restrict__ Xall, ushort* __restrict__ ZAall, ushort* __restrict__ ZBall,
    ushort* __restrict__ T1all, ushort* __restrict__ T2all, const float* __restrict__ sc)
{
  __shared__ ushort Yl[256][256];
  __shared__ ushort Btl[32][256];
  const int bt = blockIdx.x;
  const ushort* X = Xall + (long)bt * 65536;
  ushort* Z0 = ZAall + (long)bt * 65536;
  ushort* Z1 = ZBall + (long)bt * 65536;
  ushort* T1 = T1all + (long)bt * 65536;
  ushort* T2 = T2all + (long)bt * 65536;
  const int tid = threadIdx.x;
  const int lane = tid & 63, wid = tid >> 6;
  const int wr = wid >> 2, wc = wid & 3;
  const int l4 = lane >> 4, l15 = lane & 15;
  const float scale = sc[bt >> 3];

  // init Z0 = scale * X^T
  {
    int r = tid & 255, half = tid >> 8;
    for (int c0 = half * 128; c0 < half * 128 + 128; c0 += 8) {
      ushort u[8];
#pragma unroll
      for (int j = 0; j < 8; ++j)
        u[j] = f2bf(bf2f(X[(long)(c0 + j) * 256 + r]) * scale);
      *reinterpret_cast<short8*>(Z0 + (long)r * 256 + c0) = pack8u(u);
    }
  }
  gsync();

  ushort* Zc = Z0;
  ushort* Zn = Z1;
  float4v acc[8][4];

  for (int it = 0; it < 6; ++it) {
    // ---- P0: Y = X @ Zc -> LDS ----
#pragma unroll
    for (int i = 0; i < 8; ++i)
#pragma unroll
      for (int j = 0; j < 4; ++j) acc[i][j] = (float4v){0.f,0.f,0.f,0.f};
    wg_gemm256<0,0>(X, Zc, Yl, Btl, acc, tid);
    __syncthreads();
#pragma unroll
    for (int mi = 0; mi < 8; ++mi)
#pragma unroll
      for (int ni = 0; ni < 4; ++ni)
#pragma unroll
        for (int ri = 0; ri < 4; ++ri) {
          int row = wr*128 + mi*16 + l4*4 + ri;
          int col = wc*64 + ni*16 + l15;
          Yl[row][col ^ (((row >> 3) & 3) << 4)] = f2bf(acc[mi][ni][ri]);
        }
    __syncthreads();
    // ---- P1: T1 = 7Y - Y@Y ----
#pragma unroll
    for (int i = 0; i < 8; ++i)
#pragma unroll
      for (int j = 0; j < 4; ++j) acc[i][j] = (float4v){0.f,0.f,0.f,0.f};
    wg_gemm256<1,1>(nullptr, nullptr, Yl, Btl, acc, tid);
#pragma unroll
    for (int mi = 0; mi < 8; ++mi)
#pragma unroll
      for (int ni = 0; ni < 4; ++ni)
#pragma unroll
        for (int ri = 0; ri < 4; ++ri) {
          int row = wr*128 + mi*16 + l4*4 + ri;
          int col = wc*64 + ni*16 + l15;
          float y = bf2f(Yl[row][col ^ (((row >> 3) & 3) << 4)]);
          T1[(long)row*256 + col] = f2bf(7.f*y - acc[mi][ni][ri]);
        }
    gsync();
    // ---- P2: T2 = 15Y - Y@T1 ----
#pragma unroll
    for (int i = 0; i < 8; ++i)
#pragma unroll
      for (int j = 0; j < 4; ++j) acc[i][j] = (float4v){0.f,0.f,0.f,0.f};
    wg_gemm256<1,0>(nullptr, T1, Yl, Btl, acc, tid);
#pragma unroll
    for (int mi = 0; mi < 8; ++mi)
#pragma unroll
      for (int ni = 0; ni < 4; ++ni)
#pragma unroll
        for (int ri = 0; ri < 4; ++ri) {
          int row = wr*128 + mi*16 + l4*4 + ri;
          int col = wc*64 + ni*16 + l15;
          float y = bf2f(Yl[row][col ^ (((row >> 3) & 3) << 4)]);
          T2[(long)row*256 + col] = f2bf(15.f*y - acc[mi][ni][ri]);
        }
    gsync();
    // ---- P3: Zn = 0.25*(13Z - Z@T2) ----
#pragma unroll
    for (int i = 0; i < 8; ++i)
#pragma unroll
      for (int j = 0; j < 4; ++j) acc[i][j] = (float4v){0.f,0.f,0.f,0.f};
    wg_gemm256<0,0>(Zc, T2, Yl, Btl, acc, tid);
#pragma unroll
    for (int mi = 0; mi < 8; ++mi)
#pragma unroll
      for (int ni = 0; ni < 4; ++ni)
#pragma unroll
        for (int ri = 0; ri < 4; ++ri) {
          int row = wr*128 + mi*16 + l4*4 + ri;
          int col = wc*64 + ni*16 + l15;
          float zv = bf2f(Zc[(long)row*256 + col]);
          Zn[(long)row*256 + col] = f2bf(0.25f*(13.f*zv - acc[mi][ni][ri]));
        }
    gsync();
    ushort* tmp = Zc; Zc = Zn; Zn = tmp;
  }
  // 6 swaps -> final Z in ZAall
}

// z0 scale: rowsums of a softmax matrix are exactly 1, only colsum max needed.
__global__ __launch_bounds__(256) void k_colmax(const ushort* __restrict__ X, float* __restrict__ sc) {
  int cl = blockIdx.x, j = threadIdx.x;
  float cmax = 0.f;
  for (int h = 0; h < 8; ++h) {
    const ushort* mat = X + (long)(cl * 8 + h) * 65536;
    float cs = 0.f;
    for (int i = 0; i < 256; ++i) cs += bf2f(mat[i * 256 + j]);
    cmax = fmaxf(cmax, cs);
  }
  __shared__ float red[256];
  red[j] = cmax; __syncthreads();
  for (int o = 128; o > 0; o >>= 1) { if (j < o) red[j] = fmaxf(red[j], red[j + o]); __syncthreads(); }
  if (j == 0) sc[cl] = 1.f / red[0];
}

// ================= utility kernels =================
__global__ void k_prep0(const float* __restrict__ cls, const float* __restrict__ pmt, float* __restrict__ seq) {
  int i = blockIdx.x * 256 + threadIdx.x;
  if (i < 512) seq[i] = cls[i];
  else if (i < 4608) seq[i] = pmt[i - 512];
}
__global__ void k_cvt(const float* __restrict__ s, ushort* __restrict__ d, long n) {
  long i = (long)blockIdx.x * 256 + threadIdx.x;
  if (i < n) d[i] = f2bf(s[i]);
}
// all 5 weight transposes in one dispatch
__global__ void k_tcvt_all(const float* __restrict__ W1, const float* __restrict__ Wq1,
                           const float* __restrict__ Wq0, const float* __restrict__ Wo1,
                           const float* __restrict__ Wo0,
                           ushort* __restrict__ W1t, ushort* __restrict__ Wq1t,
                           ushort* __restrict__ Wq0t, ushort* __restrict__ Wo1t,
                           ushort* __restrict__ Wo0t) {
  const float* W; ushort* Wt; int K, N;
  switch (blockIdx.z) {
    case 0:  W = W1;  Wt = W1t;  K = 1024; N = 512;  break;
    case 1:  W = Wq1; Wt = Wq1t; K = 512;  N = 1536; break;
    case 2:  W = Wq0; Wt = Wq0t; K = 512;  N = 1536; break;
    case 3:  W = Wo1; Wt = Wo1t; K = 512;  N = 512;  break;
    default: W = Wo0; Wt = Wo0t; K = 512;  N = 512;  break;
  }
  int nb_ = blockIdx.x * 32, kb = blockIdx.y * 32;
  if (nb_ >= N || kb >= K) return;
  __shared__ float tile[32][33];
  int tx = threadIdx.x, ty = threadIdx.y;
  for (int r = ty; r < 32; r += 8) tile[r][tx] = W[(long)(kb + r) * N + nb_ + tx];
  __syncthreads();
  for (int r = ty; r < 32; r += 8) Wt[(long)(nb_ + r) * K + kb + tx] = f2bf(tile[tx][r]);
}

__device__ __forceinline__ void ln_row(const float* __restrict__ xr, const float* __restrict__ g,
                                       const float* __restrict__ b, ushort* __restrict__ yr,
                                       float* red, int t) {
  float v0 = xr[t], v1 = xr[t + 256];
  red[t] = v0 + v1; __syncthreads();
  for (int o = 128; o > 0; o >>= 1) { if (t < o) red[t] += red[t + o]; __syncthreads(); }
  float mu = red[0] * (1.f / E); __syncthreads();
  float d0 = v0 - mu, d1 = v1 - mu;
  red[t] = d0 * d0 + d1 * d1; __syncthreads();
  for (int o = 128; o > 0; o >>= 1) { if (t < o) red[t] += red[t + o]; __syncthreads(); }
  float inv = 1.f / sqrtf(red[0] * (1.f / E) + 1e-5f);
  yr[t]       = f2bf(d0 * inv * g[t]       + b[t]);
  yr[t + 256] = f2bf(d1 * inv * g[t + 256] + b[t + 256]);
}

// stage-B LN with front zero-padding
__global__ __launch_bounds__(256) void k_lnB(const float* __restrict__ x, const float* __restrict__ g,
                                             const float* __restrict__ b, ushort* __restrict__ y) {
  int row = blockIdx.x, t = threadIdx.x;
  ushort* yr = y + (long)row * E;
  if (row < PAD1) { yr[t] = 0; yr[t + 256] = 0; return; }
  __shared__ float red[256];
  ln_row(x + (long)(row - PAD1) * E, g, b, yr, red, t);
}
// stage-C LN: rows 0-7 = pmt, rows 8.. = tokens
__global__ __launch_bounds__(256) void k_lnC(const float* __restrict__ seq, const float* __restrict__ g,
                                             const float* __restrict__ b, ushort* __restrict__ y) {
  int row = blockIdx.x, t = threadIdx.x;
  const float* xr = (row < 8) ? (seq + 512 + (long)row * E) : (seq + 9 * 512 + (long)(row - 8) * E);
  __shared__ float red[256];
  ln_row(xr, g, b, y + (long)row * E, red, t);
}

// stage-B per-head Q,K [h][np][64] + V^T [h][64][np] in one pass
__global__ void k_buildQKVB(const float* __restrict__ qkv, ushort* __restrict__ Qb,
                            ushort* __restrict__ Kb, ushort* __restrict__ Vt) {
  int h = blockIdx.y, p0 = blockIdx.x * 64;
  int tx = threadIdx.x & 63, tg = threadIdx.x >> 6;
  __shared__ float tile[64][65];
  for (int r = tg; r < 64; r += 4) {
    long src = (long)(p0 + r) * 1536 + h * 64 + tx;
    long o = ((long)h * NPAD + p0 + r) * 64 + tx;
    Qb[o] = f2bf(qkv[src]);
    Kb[o] = f2bf(qkv[src + 512]);
    tile[r][tx] = qkv[src + 1024];
  }
  __syncthreads();
  for (int d = tg; d < 64; d += 4) Vt[((long)h * 64 + d) * NPAD + p0 + tx] = f2bf(tile[tx][d]);
}
// stage-C gathered Q,K,V^T in one pass (qkvall rows: 0-7 pmt, 8+ tokens)
__global__ void k_gatherQKV(const float* __restrict__ qkvall, const int* __restrict__ gtok,
                            ushort* __restrict__ Qg, ushort* __restrict__ Kg, ushort* __restrict__ Vgt) {
  int h = blockIdx.y, p0 = blockIdx.x * 64;
  int tx = threadIdx.x & 63, tg = threadIdx.x >> 6;
  __shared__ float tile[64][65];
  for (int r = tg; r < 64; r += 4) {
    int tk = gtok[p0 + r];
    int srcrow = tk >= 0 ? 8 + tk : (tk <= -2 ? (-2 - tk) : -1);
    float q = 0.f, k = 0.f, v = 0.f;
    if (srcrow >= 0) {
      long s = (long)srcrow * 1536 + h * 64 + tx;
      q = qkvall[s]; k = qkvall[s + 512]; v = qkvall[s + 1024];
    }
    long o = ((long)h * NG + p0 + r) * 64 + tx;
    Qg[o] = f2bf(q); Kg[o] = f2bf(k);
    tile[r][tx] = v;
  }
  __syncthreads();
  for (int d = tg; d < 64; d += 4) Vgt[((long)h * 64 + d) * NG + p0 + tx] = f2bf(tile[tx][d]);
}

__global__ void k_qlkl_B(const float* __restrict__ qkv, ushort* __restrict__ ql, ushort* __restrict__ kl,
                         float* __restrict__ mlandB) {
  int i = blockIdx.x, h = blockIdx.y, d = threadIdx.x;
  float sq = 0.f, sk = 0.f; int cnt = 0;
  for (int j = 0; j < 17; ++j) {
    int p = i * 17 + j;
    if (p >= PAD1) {
      sq += qkv[(long)p * 1536 + h * 64 + d];
      sk += qkv[(long)p * 1536 + 512 + h * 64 + d];
      cnt++;
    }
  }
  float dv = (float)cnt + 1e-8f;
  ql[((long)h * 256 + i) * 64 + d] = f2bf(sq * 0.125f / dv);
  kl[((long)h * 256 + i) * 64 + d] = f2bf(sk / dv);
  if (h == 0 && d == 0) mlandB[i] = cnt > 0 ? 1.f : 0.f;
}

__global__ void k_qlkl_C(const float* __restrict__ qkvall, const int* __restrict__ idx,
                         ushort* __restrict__ qlc, ushort* __restrict__ klc,
                         float* __restrict__ mland_c) {
  int i = blockIdx.x, bt = blockIdx.y;
  int c = bt >> 3, h = bt & 7, d = threadIdx.x;
  float sq = 0.f, sk = 0.f; int cnt = 0;
  for (int j = 0; j < 17; ++j) {
    int p = i * 17 + j;
    int srcrow = -1;
    if (p == 255) srcrow = c;
    else if (p >= 256 && idx[p - 256] == c) srcrow = 8 + (p - 256);
    if (srcrow >= 0) {
      const float* src = qkvall + (long)srcrow * 1536 + h * 64;
      sq += src[d]; sk += src[512 + d];
      cnt++;
    }
  }
  float dv = (float)cnt + 1e-8f;
  qlc[((long)bt * 256 + i) * 64 + d] = f2bf(sq * 0.125f / dv);
  klc[((long)bt * 256 + i) * 64 + d] = f2bf(sk / dv);
  if (h == 0 && d == 0) mland_c[c * 256 + i] = cnt > 0 ? 1.f : 0.f;
}

__global__ __launch_bounds__(256) void k_a2soft(const float* __restrict__ S2, const float* __restrict__ mland,
                                                ushort* __restrict__ X) {
  int i = blockIdx.x, bt = blockIdx.y, j = threadIdx.x;
  int cl = bt >> 3;
  const float* Sr = S2 + ((long)bt * 256 + i) * 256;
  __shared__ float red[256];
  float landi = mland[cl * 256 + i];
  float out;
  if (landi > 0.f) {
    bool valid = mland[cl * 256 + j] > 0.f;
    float sv = valid ? Sr[j] : NEGV;
    red[j] = sv; __syncthreads();
    for (int o = 128; o > 0; o >>= 1) { if (j < o) red[j] = fmaxf(red[j], red[j + o]); __syncthreads(); }
    float mx = red[0]; __syncthreads();
    float e = valid ? expf(sv - mx) : 0.f;
    red[j] = e; __syncthreads();
    for (int o = 128; o > 0; o >>= 1) { if (j < o) red[j] += red[j + o]; __syncthreads(); }
    out = e / red[0];
  } else {
    out = 1.f / 256.f;
  }
  X[((long)bt * 256 + i) * 256 + j] = f2bf(out);
}

// stage-B a3 softmax (NPAD cols, member = j>=PAD1)
__global__ __launch_bounds__(256) void k_smaxB_av(const float* __restrict__ S, ushort* __restrict__ P,
                                                  const float* __restrict__ mland) {
  int i = blockIdx.x, h = blockIdx.y, t = threadIdx.x;
  const float* Sr = S + ((long)h * 256 + i) * NPAD;
  ushort* Pr = P + ((long)h * 256 + i) * NPAD;
  __shared__ float sv[NPAD];
  __shared__ float red[256];
  if (mland[i] > 0.f) {
    float lmax = NEGV;
    for (int j = t; j < NPAD; j += 256) {
      float s = Sr[j];
      sv[j] = s;
      if (j >= PAD1) lmax = fmaxf(lmax, s);
    }
    red[t] = lmax; __syncthreads();
    for (int o = 128; o > 0; o >>= 1) { if (t < o) red[t] = fmaxf(red[t], red[t + o]); __syncthreads(); }
    float mx = red[0]; __syncthreads();
    float lsum = 0.f;
    for (int j = t; j < NPAD; j += 256) {
      float e = (j >= PAD1) ? expf(sv[j] - mx) : 0.f;
      sv[j] = e; lsum += e;
    }
    red[t] = lsum; __syncthreads();
    for (int o = 128; o > 0; o >>= 1) { if (t < o) red[t] += red[t + o]; __syncthreads(); }
    float inv = 1.f / red[0];
    for (int j = t; j < NPAD; j += 256) Pr[j] = f2bf(sv[j] * inv);
  } else {
    const float u = 1.f / 4352.f;
    for (int j = t; j < NPAD; j += 256) Pr[j] = f2bf(j >= PAD1 ? u : 0.f);
  }
}

// stage-C a3 softmax over gathered segment of cluster c
__global__ __launch_bounds__(256) void k_smaxseg(const float* __restrict__ S3, ushort* __restrict__ P3,
                                                 const float* __restrict__ mlandC, const int* __restrict__ gclu,
                                                 const int* __restrict__ segb) {
  int i = blockIdx.x, bt = blockIdx.y, t = threadIdx.x;
  int c = bt >> 3, h = bt & 7;
  const float* Sr = S3 + ((long)h * 256 + i) * NG;
  ushort* Pr = P3 + ((long)h * 256 + i) * NG;
  int jb = segb[c], je = segb[c + 1];
  __shared__ float sv[4352];
  __shared__ float red[256];
  if (mlandC[c * 256 + i] > 0.f) {
    float lmax = NEGV;
    for (int j = jb + t; j < je; j += 256) {
      float s = Sr[j];
      sv[j - jb] = s;
      if (gclu[j] == c) lmax = fmaxf(lmax, s);
    }
    red[t] = lmax; __syncthreads();
    for (int o = 128; o > 0; o >>= 1) { if (t < o) red[t] = fmaxf(red[t], red[t + o]); __syncthreads(); }
    float mx = red[0]; __syncthreads();
    float lsum = 0.f;
    for (int j = jb + t; j < je; j += 256) {
      float e = (gclu[j] == c) ? expf(sv[j - jb] - mx) : 0.f;
      sv[j - jb] = e; lsum += e;
    }
    red[t] = lsum; __syncthreads();
    for (int o = 128; o > 0; o >>= 1) { if (t < o) red[t] += red[t + o]; __syncthreads(); }
    float inv = 1.f / red[0];
    for (int j = jb + t; j < je; j += 256) Pr[j] = f2bf(sv[j - jb] * inv);
  } else {
    const float u = 1.f / 4352.f;
    for (int j = jb + t; j < je; j += 256) Pr[j] = f2bf(gclu[j] == c ? u : 0.f);
  }
}

// 256-col softmax for a1
template<int MODE>
__global__ __launch_bounds__(256) void k_smax256(const float* __restrict__ S, ushort* __restrict__ P,
                                                 const float* __restrict__ mland, const int* __restrict__ gtok,
                                                 const int* __restrict__ gclu, int rows) {
  int row = blockIdx.x, h = blockIdx.y, j = threadIdx.x;
  const float* Sr = S + ((long)h * rows + row) * 256;
  ushort* Pr = P + ((long)h * rows + row) * 256;
  int c = 0;
  if (MODE == 1) {
    int tk = gtok[row];
    if (tk < 0) { Pr[j] = 0; return; }
    c = gclu[row];
  }
  bool mem = (MODE == 1) ? (mland[c * 256 + j] > 0.f) : (mland[j] > 0.f);
  __shared__ float red[256];
  float s = mem ? Sr[j] : NEGV;
  red[j] = s; __syncthreads();
  for (int o = 128; o > 0; o >>= 1) { if (j < o) red[j] = fmaxf(red[j], red[j + o]); __syncthreads(); }
  float mx = red[0]; __syncthreads();
  float e = mem ? expf(s - mx) : 0.f;
  red[j] = e; __syncthreads();
  for (int o = 128; o > 0; o >>= 1) { if (j < o) red[j] += red[j + o]; __syncthreads(); }
  Pr[j] = f2bf(e / red[0]);
}

__global__ void k_avredB(const float* __restrict__ sl, ushort* __restrict__ avb, int ks) {
  int i = blockIdx.x, h = blockIdx.y, d = threadIdx.x;
  float s = 0.f;
  for (int k = 0; k < ks; ++k) s += sl[(((long)h * ks + k) * 256 + i) * 64 + d];
  avb[((long)h * 256 + i) * 64 + d] = f2bf(s);
}

// conv + bf16 output (stage B)
__global__ void k_conv_B(const float* __restrict__ qkv, const float* __restrict__ w,
                         const float* __restrict__ preout, ushort* __restrict__ lnb) {
  int r = blockIdx.x, t = threadIdx.x;     // r: 0..NSEQ-1
  int h = t >> 6;
  int prow = PAD1 + r;
  float acc = preout[(long)prow * E + t];
  for (int tt = 0; tt < 33; ++tt) {
    int p = prow + tt - 16;
    if (p < NPAD) acc += qkv[(long)p * 1536 + 1024 + t] * w[h * 33 + tt];
  }
  lnb[(long)r * E + t] = f2bf(acc);
}

// idx (blocks 0..4095) + ptc (block 4096)
__global__ void k_idxptc(const float* __restrict__ x, int* __restrict__ idx, float* __restrict__ ptc_out) {
  int t = threadIdx.x;   // 64
  __shared__ float red[64];
  if (blockIdx.x == NTOK) {
    int a = t >> 3, b = t & 7;
    const float* pmt = x + E;
    float s = 0.f;
    for (int d = 0; d < E; ++d) s += pmt[(long)a * E + d] * pmt[(long)b * E + d];
    s -= (a == b) ? 1.f : 0.f;
    red[t] = s * s; __syncthreads();
    for (int o = 32; o > 0; o >>= 1) { if (t < o) red[t] += red[t + o]; __syncthreads(); }
    if (t == 0) *ptc_out = sqrtf(red[0]);
    return;
  }
  int n = blockIdx.x;
  const float* tok = x + (long)(9 + n) * E;
  const float* pmt = x + E;
  int c = t >> 3, part = t & 7;
  float s = 0.f;
  for (int d = part * 64; d < part * 64 + 64; ++d) s += tok[d] * pmt[(long)c * E + d];
  red[t] = s; __syncthreads();
  if (t < 8) {
    float dot = 0.f;
    for (int p = 0; p < 8; ++p) dot += red[t * 8 + p];
    red[t] = dot;
  }
  __syncthreads();
  if (t == 0) {
    int best = 0; float bv = red[0];
    for (int c2 = 1; c2 < 8; ++c2) if (red[c2] > bv) { bv = red[c2]; best = c2; }
    idx[n] = best;
  }
}

// full gather prep in one deterministic block
__global__ __launch_bounds__(256) void k_gprep(const int* __restrict__ idx, int* __restrict__ gtok,
                                               int* __restrict__ gclu, int* __restrict__ gpos,
                                               int* __restrict__ segb, int* __restrict__ krange,
                                               int* __restrict__ blkclu) {
  __shared__ int hist[8][16];
  __shared__ int boff[8][16];
  __shared__ int segs[9];
  __shared__ int sidx[256];
  int t = threadIdx.x;
  if (t < 128) ((int*)hist)[t] = 0;
  __syncthreads();
  for (int b = 0; b < 16; ++b) atomicAdd(&hist[idx[b * 256 + t]][b], 1);
  __syncthreads();
  if (t == 0) {
    int s = 0;
    for (int c = 0; c < 8; ++c) {
      segs[c] = s;
      int run = s + 1, tot = 1;
      for (int b = 0; b < 16; ++b) { boff[c][b] = run; run += hist[c][b]; tot += hist[c][b]; }
      krange[2 * c] = s;
      krange[2 * c + 1] = s + ((tot + 31) & ~31);
      s += (tot + 127) & ~127;
    }
    segs[8] = s;
    for (int c = 0; c <= 8; ++c) segb[c] = segs[c];
  }
  __syncthreads();
  for (int g = t; g < NG; g += 256) { gtok[g] = -1; gclu[g] = -1; }
  __syncthreads();
  if (t < 8) { gtok[segs[t]] = -2 - t; gclu[segs[t]] = t; }
  for (int b = t; b < NG / 128; b += 256) {
    int cl = -1;
    for (int c = 0; c < 8; ++c) if (b * 128 >= segs[c] && b * 128 < segs[c + 1]) cl = c;
    blkclu[b] = cl;
  }
  for (int b = 0; b < 16; ++b) {
    int n = b * 256 + t;
    int c = idx[n];
    sidx[t] = c;
    __syncthreads();
    int rank = 0;
    for (int m = 0; m < t; ++m) rank += (sidx[m] == c);
    int pos = boff[c][b] + rank;
    gtok[pos] = n; gclu[pos] = c; gpos[n] = pos;
    __syncthreads();
  }
}

// scatter gathered a1 output + depthwise conv -> bf16 (Wout0 input)
__global__ void k_outC(const float* __restrict__ OUTg, const int* __restrict__ gpos,
                       const int* __restrict__ idx, const float* __restrict__ qkvall,
                       const float* __restrict__ w, ushort* __restrict__ lnb) {
  int n = blockIdx.x, t = threadIdx.x;   // 512
  int h = t >> 6;
  int c = idx[n];
  float acc = OUTg[(long)gpos[n] * 512 + t];
  for (int tt = 0; tt < 33; ++tt) {
    int m = n + tt - 16;
    float vv = 0.f;
    if (m == -1) vv = qkvall[(long)c * 1536 + 1024 + t];
    else if (m >= 0 && m < NTOK && idx[m] == c) vv = qkvall[(long)(8 + m) * 1536 + 1024 + t];
    acc += vv * w[h * 33 + tt];
  }
  lnb[(long)n * E + t] = f2bf(acc);
}

__global__ void k_seg_part(const float* __restrict__ hun, const int* __restrict__ idx,
                           float* __restrict__ part, float* __restrict__ pcnt) {
  int c = blockIdx.x, sl = blockIdx.y, d = threadIdx.x;
  float s = 0.f; int cnt = 0;
  for (int n = sl * 256; n < sl * 256 + 256; ++n) {
    if (idx[n] == c) { s += hun[(long)n * E + d]; if (d == 0) cnt++; }
  }
  part[(long)(c * 16 + sl) * E + d] = s;
  if (d == 0) pcnt[c * 16 + sl] = (float)cnt;
}

__global__ void k_final(const float* __restrict__ x0, const float* __restrict__ g, const float* __restrict__ b,
                        const float* __restrict__ part, const float* __restrict__ pcnt,
                        const float* __restrict__ ptc, const float* __restrict__ W3, const float* __restrict__ b3,
                        float* __restrict__ out) {
  int t = threadIdx.x;
  __shared__ float red[512];
  float xv = x0[t];
  red[t] = xv; __syncthreads();
  for (int o = 256; o > 0; o >>= 1) { if (t < o) red[t] += red[t + o]; __syncthreads(); }
  float mu = red[0] * (1.f / 512.f); __syncthreads();
  float d0 = xv - mu;
  red[t] = d0 * d0; __syncthreads();
  for (int o = 256; o > 0; o >>= 1) { if (t < o) red[t] += red[t + o]; __syncthreads(); }
  float inv = 1.f / sqrtf(red[0] * (1.f / 512.f) + 1e-5f);
  __syncthreads();
  float acc = d0 * inv * g[t] + b[t];
  for (int c = 0; c < 8; ++c) {
    float s = 0.f, cnt = 0.f;
    for (int sl = 0; sl < 16; ++sl) { s += part[(long)(c * 16 + sl) * E + t]; cnt += pcnt[c * 16 + sl]; }
    acc += s / fmaxf(cnt, 1.f);
  }
  float tk = acc * (1.f / 9.f);
  red[t] = tk * W3[t * 2 + 0]; __syncthreads();
  for (int o = 256; o > 0; o >>= 1) { if (t < o) red[t] += red[t + o]; __syncthreads(); }
  float l0 = red[0] + b3[0]; __syncthreads();
  red[t] = tk * W3[t * 2 + 1]; __syncthreads();
  for (int o = 256; o > 0; o >>= 1) { if (t < o) red[t] += red[t + o]; __syncthreads(); }
  float l1 = red[0] + b3[1];
  if (t == 0) {
    out[0] = l0; out[1] = l1;
    float mx = fmaxf(l0, l1);
    float e0 = expf(l0 - mx), e1 = expf(l1 - mx), s = e0 + e1;
    out[2] = e0 / s; out[3] = e1 / s;
    out[4] = *ptc;
  }
}

// ================= host =================
extern "C" void kernel_launch(void* const* d_in, const int* in_sizes, int n_in,
                              void* d_out, int out_size, void* d_ws, size_t ws_size,
                              hipStream_t stream) {
  const float* h_in  = (const float*)d_in[0];
  const float* W1    = (const float*)d_in[1];
  const float* b1    = (const float*)d_in[2];
  const float* cls   = (const float*)d_in[3];
  const float* pmt_t = (const float*)d_in[4];
  const float* ln1_g = (const float*)d_in[5];
  const float* ln1_b = (const float*)d_in[6];
  const float* Wqkv1 = (const float*)d_in[7];
  const float* Wout1 = (const float*)d_in[8];
  const float* bout1 = (const float*)d_in[9];
  const float* conv1 = (const float*)d_in[10];
  const float* ln0_g = (const float*)d_in[11];
  const float* ln0_b = (const float*)d_in[12];
  const float* Wqkv0 = (const float*)d_in[13];
  const float* Wout0 = (const float*)d_in[14];
  const float* bout0 = (const float*)d_in[15];
  const float* conv0 = (const float*)d_in[16];
  const float* lnf_g = (const float*)d_in[17];
  const float* lnf_b = (const float*)d_in[18];
  const float* W3    = (const float*)d_in[19];
  const float* b3    = (const float*)d_in[20];

  char* base = (char*)d_ws;
  size_t off = 0;
  auto alloc = [&](size_t b) -> void* {
    off = (off + 255) & ~(size_t)255;
    void* p = base + off; off += b; return p;
  };
  float*  SEQ    = (float*) alloc((size_t)NSEQ * E * 4);
  float*  QKV    = (float*) alloc((size_t)NPAD * 1536 * 4);
  ushort* W1t    = (ushort*)alloc((size_t)512 * 1024 * 2);
  ushort* Wq1t   = (ushort*)alloc((size_t)1536 * 512 * 2);
  ushort* Wq0t   = (ushort*)alloc((size_t)1536 * 512 * 2);
  ushort* Wo1t   = (ushort*)alloc((size_t)512 * 512 * 2);
  ushort* Wo0t   = (ushort*)alloc((size_t)512 * 512 * 2);
  ushort* LNb    = (ushort*)alloc((size_t)NPAD * E * 2);
  ushort* QbU    = (ushort*)alloc((size_t)8 * NG * 64 * 2);
  ushort* KbU    = (ushort*)alloc((size_t)8 * NG * 64 * 2);
  ushort* VtU    = (ushort*)alloc((size_t)8 * NG * 64 * 2);
  char*   U1     = (char*)  alloc((size_t)8 * 256 * NG * 4);  // 41.9 MB: hb / Sbuf / chain scratch / OUTg
  char*   U2     = (char*)  alloc((size_t)8 * 256 * NG * 2);  // 21 MB: P matrices
  ushort* PXb    = (ushort*)alloc((size_t)64 * 65536 * 2);
  ushort* PZa    = (ushort*)alloc((size_t)64 * 65536 * 2);
  ushort* qlbB   = (ushort*)alloc((size_t)8 * 16384 * 2);
  ushort* klbB   = (ushort*)alloc((size_t)8 * 16384 * 2);
  ushort* qlcb   = (ushort*)alloc((size_t)64 * 16384 * 2);
  ushort* klcb   = (ushort*)alloc((size_t)64 * 16384 * 2);
  float*  avsl   = (float*) alloc((size_t)8 * 8 * 16384 * 4);
  ushort* avb    = (ushort*)alloc((size_t)64 * 16384 * 2);
  ushort* Wcb    = (ushort*)alloc((size_t)64 * 16384 * 2);
  float*  PREOUT = (float*) alloc((size_t)NPAD * E * 4);
  float*  mlandB = (float*) alloc(256 * 4);
  float*  mlandC = (float*) alloc(8 * 256 * 4);
  int*    idx    = (int*)   alloc(NTOK * 4);
  int*    gtok   = (int*)   alloc(NG * 4);
  int*    gclu   = (int*)   alloc(NG * 4);
  int*    gpos   = (int*)   alloc(NTOK * 4);
  int*    segb   = (int*)   alloc(9 * 4);
  int*    krange = (int*)   alloc(16 * 4);
  int*    blkclu = (int*)   alloc((NG / 128) * 4);
  float*  ptc    = (float*) alloc(256);
  float*  sc     = (float*) alloc(256);
  float*  part   = (float*) alloc((size_t)8 * 16 * 512 * 4);
  float*  pcnt   = (float*) alloc(8 * 16 * 4);

  // U1 overlays
  ushort* hb   = (ushort*)U1;                                  // stage-A bf16 input
  float*  Sbuf = (float*)U1;                                   // score matrices
  ushort* ZBc  = (ushort*)U1;                                  // chain Z ping buffer
  ushort* T1c  = (ushort*)(U1 + (size_t)64 * 65536 * 2);
  ushort* T2c  = (ushort*)(U1 + (size_t)2 * 64 * 65536 * 2);
  float*  OUTg = (float*)U1;                                   // gathered a1C output
  ushort* Pbuf = (ushort*)U2;

  // ======== weights + Stage A ========
  k_tcvt_all<<<dim3(48, 32, 5), dim3(32, 8), 0, stream>>>(W1, Wqkv1, Wqkv0, Wout1, Wout0,
                                                          W1t, Wq1t, Wq0t, Wo1t, Wo0t);
  k_prep0<<<dim3(18), dim3(256), 0, stream>>>(cls, pmt_t, SEQ);
  k_cvt<<<dim3(16384), dim3(256), 0, stream>>>(h_in, hb, (long)4096 * 1024);
  mm(stream, hb, W1t, b1, nullptr, SEQ + 9 * 512, nullptr, 4096, 512, 1024, 1, 1, 512,
     0, 0, 0, nullptr, nullptr, 0, 0, nullptr, 0, 1.f, 0.f, 1 | 2, true, false);

  // ======== Stage B ========
  k_lnB<<<dim3(NPAD), dim3(256), 0, stream>>>(SEQ, ln1_g, ln1_b, LNb);
  mm(stream, LNb, Wq1t, nullptr, nullptr, QKV, nullptr, NPAD, 1536, 512, 1, 1, 1536,
     0, 0, 0, nullptr, nullptr, 0, 0, nullptr, 0, 1.f, 0.f, 0, true, false);
  k_buildQKVB<<<dim3(NPAD / 64, 8), dim3(256), 0, stream>>>(QKV, QbU, KbU, VtU);
  k_qlkl_B<<<dim3(256, 8), dim3(64), 0, stream>>>(QKV, qlbB, klbB, mlandB);
  mm(stream, qlbB, klbB, nullptr, nullptr, Sbuf, nullptr, 256, 256, 64, 8, 1, 256,
     16384, 16384, 65536, nullptr, nullptr, 0, 0, nullptr, 0, 1.f, 0.f, 0, true, false);
  k_a2soft<<<dim3(256, 8), dim3(256), 0, stream>>>(Sbuf, mlandB, PXb);
  k_colmax<<<dim3(1), dim3(256), 0, stream>>>(PXb, sc);
  k_pinv_chain<<<dim3(8), dim3(512), 0, stream>>>(PXb, PZa, ZBc, T1c, T2c, sc);
  mm(stream, qlbB, KbU, nullptr, nullptr, Sbuf, nullptr, 256, NPAD, 64, 8, 1, NPAD,
     16384, (long)NPAD * 64, (long)256 * NPAD, nullptr, nullptr, 0, 0, nullptr, 0, 1.f, 0.f, 0, true, false);
  k_smaxB_av<<<dim3(256, 8), dim3(256), 0, stream>>>(Sbuf, Pbuf, mlandB);
  mm(stream, Pbuf, VtU, nullptr, nullptr, avsl, nullptr, 256, 64, NPAD, 8, 8, 64,
     (long)256 * NPAD, (long)64 * NPAD, 16384, nullptr, nullptr, 0, 0, nullptr, 0, 1.f, 0.f, 0, true, true);
  k_avredB<<<dim3(256, 8), dim3(64), 0, stream>>>(avsl, avb, 8);
  mm(stream, PZa, avb, nullptr, nullptr, nullptr, Wcb, 256, 64, 256, 8, 1, 64,
     65536, 16384, 16384, nullptr, nullptr, 0, 0, nullptr, 0, 1.f, 0.f, 16, false, true);
  mm(stream, QbU + PAD1 * 64, klbB, nullptr, nullptr, Sbuf, nullptr, NSEQ, 256, 64, 8, 1, 256,
     (long)NPAD * 64, 16384, (long)NSEQ * 256, nullptr, nullptr, 0, 0, nullptr, 0, 0.125f, 0.f, 0, true, true);
  k_smax256<0><<<dim3(NSEQ, 8), dim3(256), 0, stream>>>(Sbuf, Pbuf, mlandB, nullptr, nullptr, NSEQ);
  mm(stream, Pbuf, Wcb, nullptr, nullptr, PREOUT + (long)PAD1 * 512, nullptr, NSEQ, 64, 256, 8, 1, 512,
     (long)NSEQ * 256, 16384, 64, nullptr, nullptr, 0, 0, nullptr, 0, 1.f, 0.f, 0, false, true);
  k_conv_B<<<dim3(NSEQ), dim3(512), 0, stream>>>(QKV, conv1, PREOUT, LNb);
  mm(stream, LNb, Wo1t, bout1, SEQ, SEQ, nullptr, NSEQ, 512, 512, 1, 1, 512,
     0, 0, 0, nullptr, nullptr, 0, 0, nullptr, 0, 1.f, 0.f, 1 | 8, true, true);   // x = seq + y

  // ======== Stage C ========
  k_idxptc<<<dim3(NTOK + 1), dim3(64), 0, stream>>>(SEQ, idx, ptc);
  k_gprep<<<dim3(1), dim3(256), 0, stream>>>(idx, gtok, gclu, gpos, segb, krange, blkclu);
  k_lnC<<<dim3(NTP), dim3(256), 0, stream>>>(SEQ, ln0_g, ln0_b, LNb);
  mm(stream, LNb, Wq0t, nullptr, nullptr, QKV, nullptr, NTP, 1536, 512, 1, 1, 1536,
     0, 0, 0, nullptr, nullptr, 0, 0, nullptr, 0, 1.f, 0.f, 0, true, true);
  k_qlkl_C<<<dim3(256, 64), dim3(64), 0, stream>>>(QKV, idx, qlcb, klcb, mlandC);
  k_gatherQKV<<<dim3(NG / 64, 8), dim3(256), 0, stream>>>(QKV, gtok, QbU, KbU, VtU);
  mm(stream, qlcb, klcb, nullptr, nullptr, Sbuf, nullptr, 256, 256, 64, 64, 1, 256,
     16384, 16384, 65536, nullptr, nullptr, 0, 0, nullptr, 0, 1.f, 0.f, 0, true, false);
  k_a2soft<<<dim3(256, 64), dim3(256), 0, stream>>>(Sbuf, mlandC, PXb);
  k_colmax<<<dim3(8), dim3(256), 0, stream>>>(PXb, sc);
  k_pinv_chain<<<dim3(64), dim3(512), 0, stream>>>(PXb, PZa, ZBc, T1c, T2c, sc);
  mm(stream, qlcb, KbU, nullptr, nullptr, Sbuf, nullptr, 256, NG, 64, 8, 1, NG,
     16384, (long)NG * 64, (long)256 * NG, blkclu, nullptr, 0, 0, nullptr, 0, 1.f, 0.f, 0, true, false);
  k_smaxseg<<<dim3(256, 64), dim3(256), 0, stream>>>(Sbuf, Pbuf, mlandC, gclu, segb);
  mm(stream, Pbuf, VtU, nullptr, nullptr, nullptr, avb, 256, 64, NG, 64, 1, 64,
     (long)256 * NG, (long)64 * NG, 16384, nullptr, nullptr, 8, 8, krange, 3, 1.f, 0.f, 16, true, true);
  mm(stream, PZa, avb, nullptr, nullptr, nullptr, Wcb, 256, 64, 256, 64, 1, 64,
     65536, 16384, 16384, nullptr, nullptr, 0, 0, nullptr, 0, 1.f, 0.f, 16, false, true);
  mm(stream, QbU, klcb, nullptr, nullptr, Sbuf, nullptr, NG, 256, 64, 8, 1, 256,
     (long)NG * 64, 16384, (long)NG * 256, nullptr, blkclu, 0, 0, nullptr, 0, 0.125f, 0.f, 0, true, false);
  k_smax256<1><<<dim3(NG, 8), dim3(256), 0, stream>>>(Sbuf, Pbuf, mlandC, gtok, gclu, NG);
  mm(stream, Pbuf, Wcb, nullptr, nullptr, OUTg, nullptr, NG, 64, 256, 8, 1, 512,
     (long)NG * 256, 16384, 64, nullptr, blkclu, 0, 0, nullptr, 0, 1.f, 0.f, 0, false, true);
  k_outC<<<dim3(NTOK), dim3(512), 0, stream>>>(OUTg, gpos, idx, QKV, conv0, LNb);
  mm(stream, LNb, Wo0t, bout0, SEQ + 9 * 512, PREOUT, nullptr, NTOK, 512, 512, 1, 1, 512,
     0, 0, 0, nullptr, nullptr, 0, 0, nullptr, 0, 1.f, 0.f, 1 | 8, true, false);   // h_un

  // ======== Final ========
  k_seg_part<<<dim3(8, 16), dim3(512), 0, stream>>>(PREOUT, idx, part, pcnt);
  k_final<<<dim3(1), dim3(512), 0, stream>>>(SEQ, lnf_g, lnf_b, part, pcnt, ptc, W3, b3,
                                             (float*)d_out);
}